// Round 3
// baseline (1749.496 us; speedup 1.0000x reference)
//
#include <hip/hip_runtime.h>

// CRF Viterbi decode: B=64, T=1024, K=256.
// emissions [B,T,K] f32, transitions [K,K] f32 (prev->next). out [B,T] f32 tags.
//
// r1 post-mortem: forward is LDS-READ-PIPE bound (~12 cyc per ds_read_b128
// per CU, broadcast or not). Fix: distribute state with ONE b128 per wave
// (lane l holds state[4l..4l+3]), reduce over the prev axis in the VALU with
// DPP hops, using an XOR-skewed slot schedule (slot j of lane (r,i) = column
// 16w + (i^j)) so the butterfly (masks 7,2,1 within half-rows, then 8)
// simultaneously reduces and transposes: lane (r,i) ends holding column i.
// All hop patterns are involutions (half_mirror=xor7, quad_perm xor2/xor1,
// ror:8=xor8 at width 16) - no rotate-direction ambiguity. Cross-row:
// ds_swizzle xor16 + shfl_xor 32.
//
// r2 post-mortem (absmax 255): gid ballot bug. hrp8 on lane (r,i) is the
// group-(2r+h) partial FOR COLUMN i^8, but it was compared against bv of
// column i (this lane's bv). Fix: fetch column i^8's bv with the same
// direction-proof ror:8 exchange (bvx) and ballot hrp8 == bvx. The bit
// extraction (indexing B1 at lane i^8 -> group 2rho+h^1) was already
// consistent with that. gid semantics (lowest 32-prev group attaining bv,
// exact float equality) identical to the proven r0 kernel -> crf_bp_gid and
// all downstream unchanged.
//
// DS/step: 16 b128 + 16 swizzle + 16 bpermute + 16 b32w (~470 cyc, was 1930).
//
// Path A: forward -> bp_gid -> seg_maps -> compose -> emit.
// Path B: forward(no gid) + bp_matrix full scan + chase.  Path C: zero.

#define CRF_B 64
#define CRF_T 1024
#define CRF_K 256
#define NSEG  16
#define SEGLEN 64

// ---------------------------------------------------------------------------
// Forward
// ---------------------------------------------------------------------------

typedef float f32x2 __attribute__((ext_vector_type(2)));

__device__ __forceinline__ f32x2 pk_add(f32x2 a, f32x2 b) {
    f32x2 d;
    asm("v_pk_add_f32 %0, %1, %2" : "=v"(d) : "v"(a), "v"(b));
    return d;
}

#define DPP_QP_XOR1    0xB1   // quad_perm [1,0,3,2]
#define DPP_QP_XOR2    0x4E   // quad_perm [2,3,0,1]
#define DPP_HALF_MIRR  0x141  // lane i -> i^7 within rows of 16
#define DPP_ROR8       0x128  // lane i <-> i^8 within rows of 16

// value from the partner lane under CTRL (exec all-on here, no bound cases)
template <int CTRL>
__device__ __forceinline__ float dpp_get(float v) {
    int s = __builtin_amdgcn_update_dpp(0, __float_as_int(v), CTRL, 0xf, 0xf,
                                        false);
    return __int_as_float(s);
}

// fmaxf(a, dpp<CTRL>(b)) ; compiler handles DPP hazard nops
template <int CTRL>
__device__ __forceinline__ float dppmax(float a, float b) {
    return fmaxf(a, dpp_get<CTRL>(b));
}

__device__ __forceinline__ float swz_xor16(float v) {
    int x = __builtin_amdgcn_ds_swizzle(__float_as_int(v), 0x401F); // xor 16
    return __int_as_float(x);
}

__global__ __launch_bounds__(1024, 4) void crf_forward_states(
    const float* __restrict__ em, const float* __restrict__ trans,
    float* __restrict__ M, unsigned char* __restrict__ gidp)
{
    const int b    = blockIdx.x;
    const int tid  = threadIdx.x;
    const int w    = tid >> 6;        // wave 0..15 -> cols 16w..16w+15
    const int lane = tid & 63;
    const int r    = lane >> 4;       // row 0..3 -> prevs 64r..64r+63
    const int i    = lane & 15;
    const int p0   = (r << 6) + (i << 2);   // my 4 prevs p0..p0+3
    const int col  = (w << 4) + i;          // my output column
    const int h    = i >> 3;                // my half within the row

    __shared__ __align__(16) float sstate[2][CRF_K];

    // Trans fragment, xor-skewed: slot j <-> column 16w + (i^j).
    f32x2 t01[16], t23[16];
#pragma unroll
    for (int j = 0; j < 16; ++j) {
        const int cj = (w << 4) + (i ^ j);
        const float* tp = trans + (size_t)p0 * CRF_K + cj;
        t01[j].x = tp[0];
        t01[j].y = tp[CRF_K];
        t23[j].x = tp[2 * CRF_K];
        t23[j].y = tp[3 * CRF_K];
    }

    const float* emb = em + (size_t)b * CRF_T * CRF_K;

    if (tid < CRF_K) sstate[0][tid] = emb[tid];       // state[0] = em[0]
    float e_cur = emb[CRF_K + col];                   // emission for t = 1
    __syncthreads();

    float* mp = M + ((size_t)CRF_B + b) * CRF_K + col;              // row t=1
    unsigned char* gp = gidp
        ? gidp + ((size_t)CRF_B + b) * 128 + (col >> 1)             // row t=1
        : nullptr;
    const float* ep = emb + 2 * CRF_K + col;                        // em[t+1]

    int cb = 0;
    for (int t = 1; t < CRF_T; ++t) {
        float e_next = 0.0f;
        if (t + 1 < CRF_T) e_next = *ep;

        const float4 sv = *((const float4*)(sstate[cb] + p0));
        const f32x2 s01 = {sv.x, sv.y};
        const f32x2 s23 = {sv.z, sv.w};

        float part[16];
#pragma unroll
        for (int j = 0; j < 16; ++j) {
            f32x2 a  = pk_add(s01, t01[j]);
            f32x2 c2 = pk_add(s23, t23[j]);
            part[j] = fmaxf(fmaxf(fmaxf(a.x, a.y), c2.x), c2.y); // max3+max
        }

        // hop xor7 (half_mirror): keep slots {0..3, 8..11}
        part[0]  = dppmax<DPP_HALF_MIRR>(part[0],  part[7]);
        part[1]  = dppmax<DPP_HALF_MIRR>(part[1],  part[6]);
        part[2]  = dppmax<DPP_HALF_MIRR>(part[2],  part[5]);
        part[3]  = dppmax<DPP_HALF_MIRR>(part[3],  part[4]);
        part[8]  = dppmax<DPP_HALF_MIRR>(part[8],  part[15]);
        part[9]  = dppmax<DPP_HALF_MIRR>(part[9],  part[14]);
        part[10] = dppmax<DPP_HALF_MIRR>(part[10], part[13]);
        part[11] = dppmax<DPP_HALF_MIRR>(part[11], part[12]);
        // hop xor2: keep {0,1,8,9}
        part[0] = dppmax<DPP_QP_XOR2>(part[0], part[2]);
        part[1] = dppmax<DPP_QP_XOR2>(part[1], part[3]);
        part[8] = dppmax<DPP_QP_XOR2>(part[8], part[10]);
        part[9] = dppmax<DPP_QP_XOR2>(part[9], part[11]);
        // hop xor1: keep {0,8}
        const float hrp0 = dppmax<DPP_QP_XOR1>(part[0], part[1]);
        const float hrp8 = dppmax<DPP_QP_XOR1>(part[8], part[9]);
        // hrp0 = half-row (32-prev group 2r+h) partial for col i
        // hrp8 = same prev group's partial for col i^8
        // hop xor8: full row partial for col i
        const float rp = dppmax<DPP_ROR8>(hrp0, hrp8);

        // cross-row: xor16 (swizzle) then xor32 (bpermute)
        float x = fmaxf(rp, swz_xor16(rp));
        const float bv = fmaxf(x, __shfl_xor(x, 32, 64));

        // new state (bv + emission), written by row 0
        if (r == 0) sstate[cb ^ 1][col] = bv + e_cur;

        // 32-prev-group argmax-group (lowest), exact float equality.
        // hrp8 refers to column i^8 -> compare against that column's bv.
        unsigned long long B0 = 0, B1 = 0;
        if (gp) {
            const float bvx = dpp_get<DPP_ROR8>(bv);   // bv of column i^8
            B0 = __ballot(hrp0 == bv);
            B1 = __ballot(hrp8 == bvx);
        }

        __syncthreads();                    // the ONLY barrier per step

        if (r == 0) *mp = bv;               // M = PRE-emission max
        mp += CRF_B * CRF_K;

        if (gp) {
            // col i bits: B0 lane (rho, i)   -> group 2*rho + h
            //             B1 lane (rho, i^8) -> group 2*rho + (h^1)
            const unsigned long long sh0 = B0 >> i;
            const unsigned long long sh1 = B1 >> (i ^ 8);
            const int h2 = h ^ 1;
            int m = 0;
            m |= ((int)(sh0      ) & 1) << (0 + h);
            m |= ((int)(sh0 >> 16) & 1) << (2 + h);
            m |= ((int)(sh0 >> 32) & 1) << (4 + h);
            m |= ((int)(sh0 >> 48) & 1) << (6 + h);
            m |= ((int)(sh1      ) & 1) << (0 + h2);
            m |= ((int)(sh1 >> 16) & 1) << (2 + h2);
            m |= ((int)(sh1 >> 32) & 1) << (4 + h2);
            m |= ((int)(sh1 >> 48) & 1) << (6 + h2);
            const int gid = __ffs(m) - 1;   // lowest matching 32-prev group
            const int g1 = __shfl_down(gid, 1, 64);
            if (r == 0 && !(i & 1))
                *gp = (unsigned char)(gid | (g1 << 4));
            gp += CRF_B * 128;
        }

        e_cur = e_next;
        ep += CRF_K;
        cb ^= 1;
    }
}

// ---------------------------------------------------------------------------
// bp via gid: 512 blocks (b x cg4 x ts2) x 256 thr (4 waves, t1 stride 4).
// 64KB transposed trans tile; gid byte for next iteration prefetched.
// ---------------------------------------------------------------------------

#define BPG_CHUNK(j) { \
    float4 mm = M4[j]; float4 ee = E4[j]; \
    float s0 = mm.x + ee.x, s1 = mm.y + ee.y; \
    float s2 = mm.z + ee.z, s3 = mm.w + ee.w; \
    float t0v = s_tile[base + 4*(j) + 0][lane]; \
    float t1v = s_tile[base + 4*(j) + 1][lane]; \
    float t2v = s_tile[base + 4*(j) + 2][lane]; \
    float t3v = s_tile[base + 4*(j) + 3][lane]; \
    float v0 = s0 + t0v; if (v0 > best) { best = v0; arg = base + 4*(j); } \
    float v1 = s1 + t1v; if (v1 > best) { best = v1; arg = base + 4*(j) + 1; } \
    float v2 = s2 + t2v; if (v2 > best) { best = v2; arg = base + 4*(j) + 2; } \
    float v3 = s3 + t3v; if (v3 > best) { best = v3; arg = base + 4*(j) + 3; } }

#define BPG_CHUNK0(j) { \
    float4 ee = E4[j]; \
    float t0v = s_tile[base + 4*(j) + 0][lane]; \
    float t1v = s_tile[base + 4*(j) + 1][lane]; \
    float t2v = s_tile[base + 4*(j) + 2][lane]; \
    float t3v = s_tile[base + 4*(j) + 3][lane]; \
    float v0 = ee.x + t0v; if (v0 > best) { best = v0; arg = base + 4*(j); } \
    float v1 = ee.y + t1v; if (v1 > best) { best = v1; arg = base + 4*(j) + 1; } \
    float v2 = ee.z + t2v; if (v2 > best) { best = v2; arg = base + 4*(j) + 2; } \
    float v3 = ee.w + t3v; if (v3 > best) { best = v3; arg = base + 4*(j) + 3; } }

__global__ __launch_bounds__(256) void crf_bp_gid(
    const float* __restrict__ M, const float* __restrict__ em,
    const float* __restrict__ trans, const unsigned char* __restrict__ gidp,
    unsigned char* __restrict__ bp)
{
    const int b    = blockIdx.x >> 3;
    const int cg   = (blockIdx.x >> 1) & 3;
    const int ts   = blockIdx.x & 1;
    const int tid  = threadIdx.x;
    const int lane = tid & 63;
    const int w    = tid >> 6;      // wave 0..3

    __shared__ float s_tile[CRF_K][64];   // 64 KB: s_tile[prev][col]

    const int k0 = cg * 64;
    for (int idx = tid; idx < CRF_K * 64; idx += 256) {
        const int p = idx >> 6, cc = idx & 63;
        s_tile[p][cc] = trans[(size_t)p * CRF_K + k0 + cc];
    }
    __syncthreads();

    const int t_lo = ts * 512;
    const int t_hi = ts ? (CRF_T - 1) : 512;
    const int half = (k0 >> 1) + (lane >> 1);
    const int odd  = lane & 1;

    int t1 = t_lo + w;
    if (t1 >= t_hi) return;
    unsigned char gb = gidp[((size_t)(t1 + 1) * CRF_B + b) * 128 + half];

    for (; t1 < t_hi; t1 += 4) {
        const int tn = t1 + 4;
        unsigned char gb_next = 0;
        if (tn < t_hi)                         // prefetch next gid byte
            gb_next = gidp[((size_t)(tn + 1) * CRF_B + b) * 128 + half];

        const int g    = odd ? ((gb >> 4) & 7) : (gb & 7);
        const int base = g << 5;
        const float4* E4 =
            (const float4*)(em + ((size_t)b * CRF_T + t1) * CRF_K + base);
        float best = -INFINITY; int arg = base;
        if (t1 == 0) {                         // state[0] = em[0]
            BPG_CHUNK0(0) BPG_CHUNK0(1) BPG_CHUNK0(2) BPG_CHUNK0(3)
            BPG_CHUNK0(4) BPG_CHUNK0(5) BPG_CHUNK0(6) BPG_CHUNK0(7)
        } else {
            const float4* M4 =
                (const float4*)(M + ((size_t)t1 * CRF_B + b) * CRF_K + base);
            BPG_CHUNK(0) BPG_CHUNK(1) BPG_CHUNK(2) BPG_CHUNK(3)
            BPG_CHUNK(4) BPG_CHUNK(5) BPG_CHUNK(6) BPG_CHUNK(7)
        }
        bp[((size_t)b * (CRF_T - 1) + t1) * CRF_K + k0 + lane] =
            (unsigned char)arg;
        gb = gb_next;
    }
}

// ---------------------------------------------------------------------------
// Fallback-B backpointers: full-scan bp_matrix (proven), state = M+em.
// ---------------------------------------------------------------------------

__global__ __launch_bounds__(1024, 2) void crf_bp_matrix(
    const float* __restrict__ M, const float* __restrict__ em,
    const float* __restrict__ trans, unsigned char* __restrict__ bp)
{
    const int b   = blockIdx.x >> 4;
    const int seg = blockIdx.x & 15;
    const int tid = threadIdx.x;
    const int g   = tid >> 8;      // 0..3
    const int k   = tid & 255;

    __shared__ __align__(16) float s_row[CRF_K];
    __shared__ float s_pv[4][CRF_K];
    __shared__ int   s_pi[4][CRF_K];

    const int pbase = g * 64;
    float4 tr[16];
#pragma unroll
    for (int i = 0; i < 16; ++i) {
        const int p = pbase + 4 * i;
        tr[i].x = trans[(p + 0) * CRF_K + k];
        tr[i].y = trans[(p + 1) * CRF_K + k];
        tr[i].z = trans[(p + 2) * CRF_K + k];
        tr[i].w = trans[(p + 3) * CRF_K + k];
    }

    const int t_lo = seg * SEGLEN;
    const int t_hi = min(t_lo + SEGLEN, CRF_T - 1);
    unsigned char* bpb = bp + (size_t)b * (CRF_T - 1) * CRF_K;

    for (int t1 = t_lo; t1 < t_hi; ++t1) {
        if (tid < CRF_K) {
            float ev = em[((size_t)b * CRF_T + t1) * CRF_K + tid];
            float sv = ev;
            if (t1 > 0) sv = M[((size_t)t1 * CRF_B + b) * CRF_K + tid] + ev;
            s_row[tid] = sv;
        }
        __syncthreads();

        float best = -INFINITY;
        int   arg  = pbase;
        const float4* spp = (const float4*)(s_row + pbase);
#pragma unroll
        for (int i = 0; i < 16; ++i) {
            float4 st = spp[i];
            const int p = pbase + 4 * i;
            float s0 = st.x + tr[i].x;
            float s1 = st.y + tr[i].y;
            float s2 = st.z + tr[i].z;
            float s3 = st.w + tr[i].w;
            if (s0 > best) { best = s0; arg = p; }
            if (s1 > best) { best = s1; arg = p + 1; }
            if (s2 > best) { best = s2; arg = p + 2; }
            if (s3 > best) { best = s3; arg = p + 3; }
        }
        s_pv[g][k] = best;
        s_pi[g][k] = arg;
        __syncthreads();
        if (tid < CRF_K) {
            float bv = s_pv[0][tid];
            int   ba = s_pi[0][tid];
#pragma unroll
            for (int j = 1; j < 4; ++j) {
                float v = s_pv[j][tid];
                if (v > bv) { bv = v; ba = s_pi[j][tid]; }
            }
            bpb[(size_t)t1 * CRF_K + tid] = (unsigned char)ba;
        }
        __syncthreads();
    }
}

// ---------------------------------------------------------------------------
// Segmented chase (proven): seg_maps -> compose -> emit.
// ---------------------------------------------------------------------------

__global__ __launch_bounds__(256) void crf_seg_maps(
    const unsigned char* __restrict__ bp, unsigned char* __restrict__ maps)
{
    const int b   = blockIdx.x >> 4;
    const int s   = blockIdx.x & 15;
    const int tid = threadIdx.x;
    const int rows = (s == NSEG - 1) ? SEGLEN - 1 : SEGLEN;
    const int r0   = s * SEGLEN;

    __shared__ unsigned char lbp[SEGLEN][CRF_K];   // 16 KB

    const unsigned char* bpb = bp + (size_t)b * (CRF_T - 1) * CRF_K;
    const int nw = rows * 64;
    for (int w = tid; w < nw; w += 256) {
        const int r = w >> 6, cc = w & 63;
        ((unsigned int*)lbp[r])[cc] =
            ((const unsigned int*)(bpb + (size_t)(r0 + r) * CRF_K))[cc];
    }
    __syncthreads();

    int tag = tid;
    for (int j = rows - 1; j >= 0; --j) tag = lbp[j][tag];
    maps[((size_t)b * NSEG + s) * CRF_K + tid] = (unsigned char)tag;
}

__global__ __launch_bounds__(256) void crf_compose(
    const float* __restrict__ M, const float* __restrict__ em,
    const unsigned char* __restrict__ maps,
    int* __restrict__ exits, float* __restrict__ out)
{
    const int b   = blockIdx.x;
    const int tid = threadIdx.x;

    __shared__ float s_wv[4];
    __shared__ int   s_wi[4];

    float v = M[((size_t)(CRF_T - 1) * CRF_B + b) * CRF_K + tid]
            + em[((size_t)b * CRF_T + (CRF_T - 1)) * CRF_K + tid];
    int   i = tid;
#pragma unroll
    for (int off = 32; off >= 1; off >>= 1) {
        float ov = __shfl_xor(v, off, 64);
        int   oi = __shfl_xor(i, off, 64);
        if (ov > v || (ov == v && oi < i)) { v = ov; i = oi; }
    }
    const int lane = tid & 63, wv = tid >> 6;
    if (lane == 0) { s_wv[wv] = v; s_wi[wv] = i; }
    __syncthreads();
    if (tid == 0) {
        float bv = s_wv[0]; int bi = s_wi[0];
#pragma unroll
        for (int w = 1; w < 4; ++w)
            if (s_wv[w] > bv) { bv = s_wv[w]; bi = s_wi[w]; }
        out[(size_t)b * CRF_T + (CRF_T - 1)] = (float)bi;
        int E = bi;
        exits[b * NSEG + NSEG - 1] = E;
        const unsigned char* mb = maps + (size_t)b * NSEG * CRF_K;
        for (int s = NSEG - 1; s >= 1; --s) {
            E = mb[(size_t)s * CRF_K + E];
            exits[b * NSEG + s - 1] = E;
        }
    }
}

__global__ __launch_bounds__(256) void crf_emit(
    const unsigned char* __restrict__ bp, const int* __restrict__ exits,
    float* __restrict__ out)
{
    const int b   = blockIdx.x >> 4;
    const int s   = blockIdx.x & 15;
    const int tid = threadIdx.x;
    const int rows = (s == NSEG - 1) ? SEGLEN - 1 : SEGLEN;
    const int r0   = s * SEGLEN;

    __shared__ unsigned char lbp[SEGLEN][CRF_K];

    const unsigned char* bpb = bp + (size_t)b * (CRF_T - 1) * CRF_K;
    const int nw = rows * 64;
    for (int w = tid; w < nw; w += 256) {
        const int r = w >> 6, cc = w & 63;
        ((unsigned int*)lbp[r])[cc] =
            ((const unsigned int*)(bpb + (size_t)(r0 + r) * CRF_K))[cc];
    }
    __syncthreads();

    int tag = tid;
    const bool win = (tid == exits[b * NSEG + s]);
    for (int j = rows - 1; j >= 0; --j) {
        tag = lbp[j][tag];
        if (win) out[(size_t)b * CRF_T + r0 + j] = (float)tag;
    }
}

__global__ void crf_zero_out(float* __restrict__ out, int n)
{
    int i = blockIdx.x * blockDim.x + threadIdx.x;
    if (i < n) out[i] = 0.0f;
}

// ---------------------------------------------------------------------------

extern "C" void kernel_launch(void* const* d_in, const int* in_sizes, int n_in,
                              void* d_out, int out_size, void* d_ws, size_t ws_size,
                              hipStream_t stream) {
    (void)in_sizes; (void)n_in;
    const float* em    = (const float*)d_in[0];   // [B,T,K]
    const float* trans = (const float*)d_in[1];   // [K,K]
    float* out = (float*)d_out;                   // [B,T]

    const size_t M_bytes     = (size_t)CRF_T * CRF_B * CRF_K * sizeof(float); // 64 MB
    const size_t gid_bytes   = (size_t)CRF_T * CRF_B * 128;                   // 8.4 MB
    const size_t bp_bytes    = (size_t)CRF_B * (CRF_T - 1) * CRF_K;           // 16.75 MB
    const size_t maps_bytes  = (size_t)CRF_B * NSEG * CRF_K;                  // 256 KB
    const size_t exits_bytes = (size_t)CRF_B * NSEG * sizeof(int);            // 4 KB

    char* w = (char*)d_ws;
    if (ws_size >= M_bytes + gid_bytes + bp_bytes + maps_bytes + exits_bytes) {
        float*         M     = (float*)w;            w += M_bytes;
        unsigned char* gidp  = (unsigned char*)w;    w += gid_bytes;
        unsigned char* bp    = (unsigned char*)w;    w += bp_bytes;
        unsigned char* maps  = (unsigned char*)w;    w += maps_bytes;
        int*           exits = (int*)w;

        crf_forward_states<<<CRF_B, 1024, 0, stream>>>(em, trans, M, gidp);
        crf_bp_gid<<<CRF_B * 8, 256, 0, stream>>>(M, em, trans, gidp, bp);
        crf_seg_maps<<<CRF_B * NSEG, 256, 0, stream>>>(bp, maps);
        crf_compose<<<CRF_B, 256, 0, stream>>>(M, em, maps, exits, out);
        crf_emit<<<CRF_B * NSEG, 256, 0, stream>>>(bp, exits, out);
    } else if (ws_size >= M_bytes + bp_bytes + maps_bytes + exits_bytes) {
        float*         M     = (float*)w;            w += M_bytes;
        unsigned char* bp    = (unsigned char*)w;    w += bp_bytes;
        unsigned char* maps  = (unsigned char*)w;    w += maps_bytes;
        int*           exits = (int*)w;

        crf_forward_states<<<CRF_B, 1024, 0, stream>>>(em, trans, M, nullptr);
        crf_bp_matrix<<<CRF_B * NSEG, 1024, 0, stream>>>(M, em, trans, bp);
        crf_seg_maps<<<CRF_B * NSEG, 256, 0, stream>>>(bp, maps);
        crf_compose<<<CRF_B, 256, 0, stream>>>(M, em, maps, exits, out);
        crf_emit<<<CRF_B * NSEG, 256, 0, stream>>>(bp, exits, out);
    } else {
        crf_zero_out<<<(out_size + 255) / 256, 256, 0, stream>>>(out, out_size);
    }
}

// Round 4
// 1544.921 us; speedup vs baseline: 1.1324x; 1.1324x over previous
//
#include <hip/hip_runtime.h>

// CRF Viterbi decode: B=64, T=1024, K=256.
// emissions [B,T,K] f32, transitions [K,K] f32 (prev->next). out [B,T] f32 tags.
//
// r1 post-mortem: forward is LDS-READ-PIPE bound (~12 cyc per ds_read_b128
// per CU, broadcast or not). Fix: distribute state with ONE b128 per wave
// (lane l holds state[4l..4l+3]), reduce over the prev axis in the VALU with
// DPP hops, using an XOR-skewed slot schedule (slot j of lane (r,i) = column
// 16w + (i^j)) so the butterfly (masks 7,2,1 within half-rows, then 8)
// simultaneously reduces and transposes: lane (r,i) ends holding column i.
// All hop patterns are involutions - no rotate-direction ambiguity.
// Cross-row: ds_swizzle xor16 + shfl_xor 32.
//
// r2 post-mortem (absmax 255): gid ballot compared hrp8 (a col-i^8 partial)
// against col i's bv. Fixed in r3 with bvx = dpp_ror8(bv); PROVEN (absmax 0).
//
// r3 post-mortem (1472us, VALU 345 instr/wave/step vs ~130 expected): the
// inline-asm v_pk_add_f32 with "v" constraints forced AGPR-resident trans
// values through arch-VGPR copies (v_accvgpr_read/write around each of 32
// pk_adds/step). VGPR_Count=52 while ~100 values live => surplus in AGPRs
// (fine on CDNA: VALU reads AGPRs directly) but asm "v" defeats that.
// r4 fix: native ext_vector float2 adds (LLVM selects v_pk_add_f32 on
// gfx90a+ without operand coercion). Identical f32 adds + identical fmax
// tree => bit-exact vs r3; gid/bp/downstream untouched.
//
// Path A: forward -> bp_gid -> seg_maps -> compose -> emit.
// Path B: forward(no gid) + bp_matrix full scan + chase.  Path C: zero.

#define CRF_B 64
#define CRF_T 1024
#define CRF_K 256
#define NSEG  16
#define SEGLEN 64

// ---------------------------------------------------------------------------
// Forward
// ---------------------------------------------------------------------------

typedef float f32x2 __attribute__((ext_vector_type(2)));

#define DPP_QP_XOR1    0xB1   // quad_perm [1,0,3,2]
#define DPP_QP_XOR2    0x4E   // quad_perm [2,3,0,1]
#define DPP_HALF_MIRR  0x141  // lane i -> i^7 within rows of 16
#define DPP_ROR8       0x128  // lane i <-> i^8 within rows of 16

// value from the partner lane under CTRL (exec all-on here, no bound cases)
template <int CTRL>
__device__ __forceinline__ float dpp_get(float v) {
    int s = __builtin_amdgcn_update_dpp(0, __float_as_int(v), CTRL, 0xf, 0xf,
                                        false);
    return __int_as_float(s);
}

// fmaxf(a, dpp<CTRL>(b)) ; GCNDPPCombine may fuse mov_dpp into v_max
template <int CTRL>
__device__ __forceinline__ float dppmax(float a, float b) {
    return fmaxf(a, dpp_get<CTRL>(b));
}

__device__ __forceinline__ float swz_xor16(float v) {
    int x = __builtin_amdgcn_ds_swizzle(__float_as_int(v), 0x401F); // xor 16
    return __int_as_float(x);
}

__global__ __launch_bounds__(1024, 4) void crf_forward_states(
    const float* __restrict__ em, const float* __restrict__ trans,
    float* __restrict__ M, unsigned char* __restrict__ gidp)
{
    const int b    = blockIdx.x;
    const int tid  = threadIdx.x;
    const int w    = tid >> 6;        // wave 0..15 -> cols 16w..16w+15
    const int lane = tid & 63;
    const int r    = lane >> 4;       // row 0..3 -> prevs 64r..64r+63
    const int i    = lane & 15;
    const int p0   = (r << 6) + (i << 2);   // my 4 prevs p0..p0+3
    const int col  = (w << 4) + i;          // my output column
    const int h    = i >> 3;                // my half within the row

    __shared__ __align__(16) float sstate[2][CRF_K];

    // Trans fragment, xor-skewed: slot j <-> column 16w + (i^j).
    f32x2 t01[16], t23[16];
#pragma unroll
    for (int j = 0; j < 16; ++j) {
        const int cj = (w << 4) + (i ^ j);
        const float* tp = trans + (size_t)p0 * CRF_K + cj;
        t01[j].x = tp[0];
        t01[j].y = tp[CRF_K];
        t23[j].x = tp[2 * CRF_K];
        t23[j].y = tp[3 * CRF_K];
    }

    const float* emb = em + (size_t)b * CRF_T * CRF_K;

    if (tid < CRF_K) sstate[0][tid] = emb[tid];       // state[0] = em[0]
    float e_cur = emb[CRF_K + col];                   // emission for t = 1
    __syncthreads();

    float* mp = M + ((size_t)CRF_B + b) * CRF_K + col;              // row t=1
    unsigned char* gp = gidp
        ? gidp + ((size_t)CRF_B + b) * 128 + (col >> 1)             // row t=1
        : nullptr;
    const float* ep = emb + 2 * CRF_K + col;                        // em[t+1]

    int cb = 0;
    for (int t = 1; t < CRF_T; ++t) {
        float e_next = 0.0f;
        if (t + 1 < CRF_T) e_next = *ep;

        const float4 sv = *((const float4*)(sstate[cb] + p0));
        f32x2 s01; s01.x = sv.x; s01.y = sv.y;
        f32x2 s23; s23.x = sv.z; s23.y = sv.w;

        float part[16];
#pragma unroll
        for (int j = 0; j < 16; ++j) {
            const f32x2 a  = s01 + t01[j];      // v_pk_add_f32 (native)
            const f32x2 c2 = s23 + t23[j];      // v_pk_add_f32 (native)
            part[j] = fmaxf(fmaxf(fmaxf(a.x, a.y), c2.x), c2.y); // max3+max
        }

        // hop xor7 (half_mirror): keep slots {0..3, 8..11}
        part[0]  = dppmax<DPP_HALF_MIRR>(part[0],  part[7]);
        part[1]  = dppmax<DPP_HALF_MIRR>(part[1],  part[6]);
        part[2]  = dppmax<DPP_HALF_MIRR>(part[2],  part[5]);
        part[3]  = dppmax<DPP_HALF_MIRR>(part[3],  part[4]);
        part[8]  = dppmax<DPP_HALF_MIRR>(part[8],  part[15]);
        part[9]  = dppmax<DPP_HALF_MIRR>(part[9],  part[14]);
        part[10] = dppmax<DPP_HALF_MIRR>(part[10], part[13]);
        part[11] = dppmax<DPP_HALF_MIRR>(part[11], part[12]);
        // hop xor2: keep {0,1,8,9}
        part[0] = dppmax<DPP_QP_XOR2>(part[0], part[2]);
        part[1] = dppmax<DPP_QP_XOR2>(part[1], part[3]);
        part[8] = dppmax<DPP_QP_XOR2>(part[8], part[10]);
        part[9] = dppmax<DPP_QP_XOR2>(part[9], part[11]);
        // hop xor1: keep {0,8}
        const float hrp0 = dppmax<DPP_QP_XOR1>(part[0], part[1]);
        const float hrp8 = dppmax<DPP_QP_XOR1>(part[8], part[9]);
        // hrp0 = half-row (32-prev group 2r+h) partial for col i
        // hrp8 = same prev group's partial for col i^8
        // hop xor8: full row partial for col i
        const float rp = dppmax<DPP_ROR8>(hrp0, hrp8);

        // cross-row: xor16 (swizzle) then xor32 (bpermute)
        float x = fmaxf(rp, swz_xor16(rp));
        const float bv = fmaxf(x, __shfl_xor(x, 32, 64));

        // new state (bv + emission), written by row 0
        if (r == 0) sstate[cb ^ 1][col] = bv + e_cur;

        // 32-prev-group argmax-group (lowest), exact float equality.
        // hrp8 refers to column i^8 -> compare against that column's bv.
        unsigned long long B0 = 0, B1 = 0;
        if (gp) {
            const float bvx = dpp_get<DPP_ROR8>(bv);   // bv of column i^8
            B0 = __ballot(hrp0 == bv);
            B1 = __ballot(hrp8 == bvx);
        }

        __syncthreads();                    // the ONLY barrier per step

        if (r == 0) *mp = bv;               // M = PRE-emission max
        mp += CRF_B * CRF_K;

        if (gp) {
            // col i bits: B0 lane (rho, i)   -> group 2*rho + h
            //             B1 lane (rho, i^8) -> group 2*rho + (h^1)
            const unsigned long long sh0 = B0 >> i;
            const unsigned long long sh1 = B1 >> (i ^ 8);
            const int h2 = h ^ 1;
            int m = 0;
            m |= ((int)(sh0      ) & 1) << (0 + h);
            m |= ((int)(sh0 >> 16) & 1) << (2 + h);
            m |= ((int)(sh0 >> 32) & 1) << (4 + h);
            m |= ((int)(sh0 >> 48) & 1) << (6 + h);
            m |= ((int)(sh1      ) & 1) << (0 + h2);
            m |= ((int)(sh1 >> 16) & 1) << (2 + h2);
            m |= ((int)(sh1 >> 32) & 1) << (4 + h2);
            m |= ((int)(sh1 >> 48) & 1) << (6 + h2);
            const int gid = __ffs(m) - 1;   // lowest matching 32-prev group
            const int g1 = __shfl_down(gid, 1, 64);
            if (r == 0 && !(i & 1))
                *gp = (unsigned char)(gid | (g1 << 4));
            gp += CRF_B * 128;
        }

        e_cur = e_next;
        ep += CRF_K;
        cb ^= 1;
    }
}

// ---------------------------------------------------------------------------
// bp via gid: 512 blocks (b x cg4 x ts2) x 256 thr (4 waves, t1 stride 4).
// 64KB transposed trans tile; gid byte for next iteration prefetched.
// ---------------------------------------------------------------------------

#define BPG_CHUNK(j) { \
    float4 mm = M4[j]; float4 ee = E4[j]; \
    float s0 = mm.x + ee.x, s1 = mm.y + ee.y; \
    float s2 = mm.z + ee.z, s3 = mm.w + ee.w; \
    float t0v = s_tile[base + 4*(j) + 0][lane]; \
    float t1v = s_tile[base + 4*(j) + 1][lane]; \
    float t2v = s_tile[base + 4*(j) + 2][lane]; \
    float t3v = s_tile[base + 4*(j) + 3][lane]; \
    float v0 = s0 + t0v; if (v0 > best) { best = v0; arg = base + 4*(j); } \
    float v1 = s1 + t1v; if (v1 > best) { best = v1; arg = base + 4*(j) + 1; } \
    float v2 = s2 + t2v; if (v2 > best) { best = v2; arg = base + 4*(j) + 2; } \
    float v3 = s3 + t3v; if (v3 > best) { best = v3; arg = base + 4*(j) + 3; } }

#define BPG_CHUNK0(j) { \
    float4 ee = E4[j]; \
    float t0v = s_tile[base + 4*(j) + 0][lane]; \
    float t1v = s_tile[base + 4*(j) + 1][lane]; \
    float t2v = s_tile[base + 4*(j) + 2][lane]; \
    float t3v = s_tile[base + 4*(j) + 3][lane]; \
    float v0 = ee.x + t0v; if (v0 > best) { best = v0; arg = base + 4*(j); } \
    float v1 = ee.y + t1v; if (v1 > best) { best = v1; arg = base + 4*(j) + 1; } \
    float v2 = ee.z + t2v; if (v2 > best) { best = v2; arg = base + 4*(j) + 2; } \
    float v3 = ee.w + t3v; if (v3 > best) { best = v3; arg = base + 4*(j) + 3; } }

__global__ __launch_bounds__(256) void crf_bp_gid(
    const float* __restrict__ M, const float* __restrict__ em,
    const float* __restrict__ trans, const unsigned char* __restrict__ gidp,
    unsigned char* __restrict__ bp)
{
    const int b    = blockIdx.x >> 3;
    const int cg   = (blockIdx.x >> 1) & 3;
    const int ts   = blockIdx.x & 1;
    const int tid  = threadIdx.x;
    const int lane = tid & 63;
    const int w    = tid >> 6;      // wave 0..3

    __shared__ float s_tile[CRF_K][64];   // 64 KB: s_tile[prev][col]

    const int k0 = cg * 64;
    for (int idx = tid; idx < CRF_K * 64; idx += 256) {
        const int p = idx >> 6, cc = idx & 63;
        s_tile[p][cc] = trans[(size_t)p * CRF_K + k0 + cc];
    }
    __syncthreads();

    const int t_lo = ts * 512;
    const int t_hi = ts ? (CRF_T - 1) : 512;
    const int half = (k0 >> 1) + (lane >> 1);
    const int odd  = lane & 1;

    int t1 = t_lo + w;
    if (t1 >= t_hi) return;
    unsigned char gb = gidp[((size_t)(t1 + 1) * CRF_B + b) * 128 + half];

    for (; t1 < t_hi; t1 += 4) {
        const int tn = t1 + 4;
        unsigned char gb_next = 0;
        if (tn < t_hi)                         // prefetch next gid byte
            gb_next = gidp[((size_t)(tn + 1) * CRF_B + b) * 128 + half];

        const int g    = odd ? ((gb >> 4) & 7) : (gb & 7);
        const int base = g << 5;
        const float4* E4 =
            (const float4*)(em + ((size_t)b * CRF_T + t1) * CRF_K + base);
        float best = -INFINITY; int arg = base;
        if (t1 == 0) {                         // state[0] = em[0]
            BPG_CHUNK0(0) BPG_CHUNK0(1) BPG_CHUNK0(2) BPG_CHUNK0(3)
            BPG_CHUNK0(4) BPG_CHUNK0(5) BPG_CHUNK0(6) BPG_CHUNK0(7)
        } else {
            const float4* M4 =
                (const float4*)(M + ((size_t)t1 * CRF_B + b) * CRF_K + base);
            BPG_CHUNK(0) BPG_CHUNK(1) BPG_CHUNK(2) BPG_CHUNK(3)
            BPG_CHUNK(4) BPG_CHUNK(5) BPG_CHUNK(6) BPG_CHUNK(7)
        }
        bp[((size_t)b * (CRF_T - 1) + t1) * CRF_K + k0 + lane] =
            (unsigned char)arg;
        gb = gb_next;
    }
}

// ---------------------------------------------------------------------------
// Fallback-B backpointers: full-scan bp_matrix (proven), state = M+em.
// ---------------------------------------------------------------------------

__global__ __launch_bounds__(1024, 2) void crf_bp_matrix(
    const float* __restrict__ M, const float* __restrict__ em,
    const float* __restrict__ trans, unsigned char* __restrict__ bp)
{
    const int b   = blockIdx.x >> 4;
    const int seg = blockIdx.x & 15;
    const int tid = threadIdx.x;
    const int g   = tid >> 8;      // 0..3
    const int k   = tid & 255;

    __shared__ __align__(16) float s_row[CRF_K];
    __shared__ float s_pv[4][CRF_K];
    __shared__ int   s_pi[4][CRF_K];

    const int pbase = g * 64;
    float4 tr[16];
#pragma unroll
    for (int i = 0; i < 16; ++i) {
        const int p = pbase + 4 * i;
        tr[i].x = trans[(p + 0) * CRF_K + k];
        tr[i].y = trans[(p + 1) * CRF_K + k];
        tr[i].z = trans[(p + 2) * CRF_K + k];
        tr[i].w = trans[(p + 3) * CRF_K + k];
    }

    const int t_lo = seg * SEGLEN;
    const int t_hi = min(t_lo + SEGLEN, CRF_T - 1);
    unsigned char* bpb = bp + (size_t)b * (CRF_T - 1) * CRF_K;

    for (int t1 = t_lo; t1 < t_hi; ++t1) {
        if (tid < CRF_K) {
            float ev = em[((size_t)b * CRF_T + t1) * CRF_K + tid];
            float sv = ev;
            if (t1 > 0) sv = M[((size_t)t1 * CRF_B + b) * CRF_K + tid] + ev;
            s_row[tid] = sv;
        }
        __syncthreads();

        float best = -INFINITY;
        int   arg  = pbase;
        const float4* spp = (const float4*)(s_row + pbase);
#pragma unroll
        for (int i = 0; i < 16; ++i) {
            float4 st = spp[i];
            const int p = pbase + 4 * i;
            float s0 = st.x + tr[i].x;
            float s1 = st.y + tr[i].y;
            float s2 = st.z + tr[i].z;
            float s3 = st.w + tr[i].w;
            if (s0 > best) { best = s0; arg = p; }
            if (s1 > best) { best = s1; arg = p + 1; }
            if (s2 > best) { best = s2; arg = p + 2; }
            if (s3 > best) { best = s3; arg = p + 3; }
        }
        s_pv[g][k] = best;
        s_pi[g][k] = arg;
        __syncthreads();
        if (tid < CRF_K) {
            float bv = s_pv[0][tid];
            int   ba = s_pi[0][tid];
#pragma unroll
            for (int j = 1; j < 4; ++j) {
                float v = s_pv[j][tid];
                if (v > bv) { bv = v; ba = s_pi[j][tid]; }
            }
            bpb[(size_t)t1 * CRF_K + tid] = (unsigned char)ba;
        }
        __syncthreads();
    }
}

// ---------------------------------------------------------------------------
// Segmented chase (proven): seg_maps -> compose -> emit.
// ---------------------------------------------------------------------------

__global__ __launch_bounds__(256) void crf_seg_maps(
    const unsigned char* __restrict__ bp, unsigned char* __restrict__ maps)
{
    const int b   = blockIdx.x >> 4;
    const int s   = blockIdx.x & 15;
    const int tid = threadIdx.x;
    const int rows = (s == NSEG - 1) ? SEGLEN - 1 : SEGLEN;
    const int r0   = s * SEGLEN;

    __shared__ unsigned char lbp[SEGLEN][CRF_K];   // 16 KB

    const unsigned char* bpb = bp + (size_t)b * (CRF_T - 1) * CRF_K;
    const int nw = rows * 64;
    for (int w = tid; w < nw; w += 256) {
        const int r = w >> 6, cc = w & 63;
        ((unsigned int*)lbp[r])[cc] =
            ((const unsigned int*)(bpb + (size_t)(r0 + r) * CRF_K))[cc];
    }
    __syncthreads();

    int tag = tid;
    for (int j = rows - 1; j >= 0; --j) tag = lbp[j][tag];
    maps[((size_t)b * NSEG + s) * CRF_K + tid] = (unsigned char)tag;
}

__global__ __launch_bounds__(256) void crf_compose(
    const float* __restrict__ M, const float* __restrict__ em,
    const unsigned char* __restrict__ maps,
    int* __restrict__ exits, float* __restrict__ out)
{
    const int b   = blockIdx.x;
    const int tid = threadIdx.x;

    __shared__ float s_wv[4];
    __shared__ int   s_wi[4];

    float v = M[((size_t)(CRF_T - 1) * CRF_B + b) * CRF_K + tid]
            + em[((size_t)b * CRF_T + (CRF_T - 1)) * CRF_K + tid];
    int   i = tid;
#pragma unroll
    for (int off = 32; off >= 1; off >>= 1) {
        float ov = __shfl_xor(v, off, 64);
        int   oi = __shfl_xor(i, off, 64);
        if (ov > v || (ov == v && oi < i)) { v = ov; i = oi; }
    }
    const int lane = tid & 63, wv = tid >> 6;
    if (lane == 0) { s_wv[wv] = v; s_wi[wv] = i; }
    __syncthreads();
    if (tid == 0) {
        float bv = s_wv[0]; int bi = s_wi[0];
#pragma unroll
        for (int w = 1; w < 4; ++w)
            if (s_wv[w] > bv) { bv = s_wv[w]; bi = s_wi[w]; }
        out[(size_t)b * CRF_T + (CRF_T - 1)] = (float)bi;
        int E = bi;
        exits[b * NSEG + NSEG - 1] = E;
        const unsigned char* mb = maps + (size_t)b * NSEG * CRF_K;
        for (int s = NSEG - 1; s >= 1; --s) {
            E = mb[(size_t)s * CRF_K + E];
            exits[b * NSEG + s - 1] = E;
        }
    }
}

__global__ __launch_bounds__(256) void crf_emit(
    const unsigned char* __restrict__ bp, const int* __restrict__ exits,
    float* __restrict__ out)
{
    const int b   = blockIdx.x >> 4;
    const int s   = blockIdx.x & 15;
    const int tid = threadIdx.x;
    const int rows = (s == NSEG - 1) ? SEGLEN - 1 : SEGLEN;
    const int r0   = s * SEGLEN;

    __shared__ unsigned char lbp[SEGLEN][CRF_K];

    const unsigned char* bpb = bp + (size_t)b * (CRF_T - 1) * CRF_K;
    const int nw = rows * 64;
    for (int w = tid; w < nw; w += 256) {
        const int r = w >> 6, cc = w & 63;
        ((unsigned int*)lbp[r])[cc] =
            ((const unsigned int*)(bpb + (size_t)(r0 + r) * CRF_K))[cc];
    }
    __syncthreads();

    int tag = tid;
    const bool win = (tid == exits[b * NSEG + s]);
    for (int j = rows - 1; j >= 0; --j) {
        tag = lbp[j][tag];
        if (win) out[(size_t)b * CRF_T + r0 + j] = (float)tag;
    }
}

__global__ void crf_zero_out(float* __restrict__ out, int n)
{
    int i = blockIdx.x * blockDim.x + threadIdx.x;
    if (i < n) out[i] = 0.0f;
}

// ---------------------------------------------------------------------------

extern "C" void kernel_launch(void* const* d_in, const int* in_sizes, int n_in,
                              void* d_out, int out_size, void* d_ws, size_t ws_size,
                              hipStream_t stream) {
    (void)in_sizes; (void)n_in;
    const float* em    = (const float*)d_in[0];   // [B,T,K]
    const float* trans = (const float*)d_in[1];   // [K,K]
    float* out = (float*)d_out;                   // [B,T]

    const size_t M_bytes     = (size_t)CRF_T * CRF_B * CRF_K * sizeof(float); // 64 MB
    const size_t gid_bytes   = (size_t)CRF_T * CRF_B * 128;                   // 8.4 MB
    const size_t bp_bytes    = (size_t)CRF_B * (CRF_T - 1) * CRF_K;           // 16.75 MB
    const size_t maps_bytes  = (size_t)CRF_B * NSEG * CRF_K;                  // 256 KB
    const size_t exits_bytes = (size_t)CRF_B * NSEG * sizeof(int);            // 4 KB

    char* w = (char*)d_ws;
    if (ws_size >= M_bytes + gid_bytes + bp_bytes + maps_bytes + exits_bytes) {
        float*         M     = (float*)w;            w += M_bytes;
        unsigned char* gidp  = (unsigned char*)w;    w += gid_bytes;
        unsigned char* bp    = (unsigned char*)w;    w += bp_bytes;
        unsigned char* maps  = (unsigned char*)w;    w += maps_bytes;
        int*           exits = (int*)w;

        crf_forward_states<<<CRF_B, 1024, 0, stream>>>(em, trans, M, gidp);
        crf_bp_gid<<<CRF_B * 8, 256, 0, stream>>>(M, em, trans, gidp, bp);
        crf_seg_maps<<<CRF_B * NSEG, 256, 0, stream>>>(bp, maps);
        crf_compose<<<CRF_B, 256, 0, stream>>>(M, em, maps, exits, out);
        crf_emit<<<CRF_B * NSEG, 256, 0, stream>>>(bp, exits, out);
    } else if (ws_size >= M_bytes + bp_bytes + maps_bytes + exits_bytes) {
        float*         M     = (float*)w;            w += M_bytes;
        unsigned char* bp    = (unsigned char*)w;    w += bp_bytes;
        unsigned char* maps  = (unsigned char*)w;    w += maps_bytes;
        int*           exits = (int*)w;

        crf_forward_states<<<CRF_B, 1024, 0, stream>>>(em, trans, M, nullptr);
        crf_bp_matrix<<<CRF_B * NSEG, 1024, 0, stream>>>(M, em, trans, bp);
        crf_seg_maps<<<CRF_B * NSEG, 256, 0, stream>>>(bp, maps);
        crf_compose<<<CRF_B, 256, 0, stream>>>(M, em, maps, exits, out);
        crf_emit<<<CRF_B * NSEG, 256, 0, stream>>>(bp, exits, out);
    } else {
        crf_zero_out<<<(out_size + 255) / 256, 256, 0, stream>>>(out, out_size);
    }
}

// Round 5
// 1262.412 us; speedup vs baseline: 1.3858x; 1.2238x over previous
//
#include <hip/hip_runtime.h>

// CRF Viterbi decode: B=64, T=1024, K=256.
// emissions [B,T,K] f32, transitions [K,K] f32 (prev->next). out [B,T] f32 tags.
//
// History: r0 (815us fwd) = 2-phase broadcast structure, LDS-read-pipe bound
// (128 broadcast ds_read_b128/step ~= 1944 cyc model vs 1912 measured).
// r2-r4 (DPP full-redesign) = minimal LDS but latency-chain bound (VALU 39%,
// LDS 25%, rest stall) -> slower. r5 synthesis: keep r0's proven 2-phase
// structure verbatim, replace ONLY the broadcast reads: quad-lane qi loads
// state chunks {2qi,2qi+1} (2 per-lane b128/wave instead of 8 broadcast
// b128/wave) and chunks are shared within each quad via DPP quad_perm
// broadcast movs (compile-time ctrl 0x55*S). Broadcast values bit-identical
// to the old sp[idx] reads, same add/max order -> bit-exact. Adds remain
// vanilla VOP3 v_add_f32 sourcing AGPR-resident trans (r0-proven codegen).
// LDS instrs/step: 196 -> ~100 (32 b128 + 68 b32 ~= 800 cyc, was ~1944).
//
//   1. crf_forward_states : 2-phase; reducer = cheap max3 tree; gid
//      (first 32-prev group attaining the max) computed DEFERRED one step
//      later, overlapped with the next step's chunk compute.
//   2. crf_bp_gid         : 4 waves/block + gid prefetch pipeline.
//   3. crf_seg_maps / crf_compose / crf_emit : proven segmented chase.
// Path B: forward(no gid) + bp_matrix full scan + chase.  Path C: zero.

#define CRF_B 64
#define CRF_T 1024
#define CRF_K 256
#define NSEG  16
#define SEGLEN 64

#define FG 8
#define FP 32

// ---------------------------------------------------------------------------
// Forward
// ---------------------------------------------------------------------------

#define LD4(v, p, col) { \
    v.x = trans[(size_t)(p) * CRF_K + (col)]; \
    v.y = trans[(size_t)((p) + 1) * CRF_K + (col)]; \
    v.z = trans[(size_t)((p) + 2) * CRF_K + (col)]; \
    v.w = trans[(size_t)((p) + 3) * CRF_K + (col)]; }

// quad_perm broadcast: every lane gets quad-lane S's value (ctrl = S*0x55)
template <int S>
__device__ __forceinline__ float qb(float v) {
    return __int_as_float(__builtin_amdgcn_update_dpp(
        0, __float_as_int(v), 0x55 * S, 0xf, 0xf, false));
}

// chunk data arrives via quad broadcast of S4 (held by quad-lane S);
// identical values and identical add/max order as the old sp[idx] read.
#define FWD_CHUNK_Q(S4, S, ta, tb) { \
    float x0 = qb<S>(S4.x); \
    float x1 = qb<S>(S4.y); \
    float x2 = qb<S>(S4.z); \
    float x3 = qb<S>(S4.w); \
    float a0 = x0 + ta.x; \
    float a1 = x1 + ta.y; \
    float a2 = x2 + ta.z; \
    float a3 = x3 + ta.w; \
    float q0 = fmaxf(fmaxf(a0, a1), a2); \
    m0 = fmaxf(fmaxf(q0, a3), m0); \
    float c0 = x0 + tb.x; \
    float c1 = x1 + tb.y; \
    float c2 = x2 + tb.z; \
    float c3 = x3 + tb.w; \
    float q1 = fmaxf(fmaxf(c0, c1), c2); \
    m1 = fmaxf(fmaxf(q1, c3), m1); }

__global__ __launch_bounds__(1024, 4) void crf_forward_states(
    const float* __restrict__ em, const float* __restrict__ trans,
    float* __restrict__ M, unsigned char* __restrict__ gidp)
{
    const int b   = blockIdx.x;
    const int tid = threadIdx.x;
    const int g   = tid >> 7;      // prev group 0..7
    const int c   = tid & 127;     // columns c and c+128
    const int qi  = tid & 3;       // quad-lane 0..3

    __shared__ __align__(16) float s_state[CRF_K];
    __shared__ float s_partial[FG][CRF_K];

    const int pbase = g * FP;
    const int c2    = c + 128;

    float4 ta0, ta1, ta2, ta3, ta4, ta5, ta6, ta7;
    float4 tb0, tb1, tb2, tb3, tb4, tb5, tb6, tb7;
    LD4(ta0, pbase +  0, c)  LD4(ta1, pbase +  4, c)
    LD4(ta2, pbase +  8, c)  LD4(ta3, pbase + 12, c)
    LD4(ta4, pbase + 16, c)  LD4(ta5, pbase + 20, c)
    LD4(ta6, pbase + 24, c)  LD4(ta7, pbase + 28, c)
    LD4(tb0, pbase +  0, c2) LD4(tb1, pbase +  4, c2)
    LD4(tb2, pbase +  8, c2) LD4(tb3, pbase + 12, c2)
    LD4(tb4, pbase + 16, c2) LD4(tb5, pbase + 20, c2)
    LD4(tb6, pbase + 24, c2) LD4(tb7, pbase + 28, c2)

    const float* emb = em + (size_t)b * CRF_T * CRF_K;
    if (tid < CRF_K) s_state[tid] = emb[tid];          // state[0] = em[0]
    float e_cur = 0.0f;
    if (tid < CRF_K) e_cur = emb[CRF_K + tid];         // emission for t = 1
    __syncthreads();

    // deferred-gid state (saved across the barrier; stored one step later)
    float sp0 = 0, sp1 = 0, sp2 = 0, sp3 = 0;
    float sp4 = 0, sp5 = 0, sp6 = 0, sp7 = 0;
    float sbv = 0;

    for (int t = 1; t < CRF_T; ++t) {
        // deferred gid store for step t-1 (reads saved regs only; overlaps
        // all waves' chunk compute instead of the serial reducer section)
        if (gidp && tid < CRF_K && t > 1) {
            int bg = 7;
            if (sp6 == sbv) bg = 6;
            if (sp5 == sbv) bg = 5;
            if (sp4 == sbv) bg = 4;
            if (sp3 == sbv) bg = 3;
            if (sp2 == sbv) bg = 2;
            if (sp1 == sbv) bg = 1;
            if (sp0 == sbv) bg = 0;
            int g1 = __shfl_down(bg, 1, 64);
            if ((tid & 1) == 0)
                gidp[((size_t)(t - 1) * CRF_B + b) * 128 + (tid >> 1)] =
                    (unsigned char)(bg | (g1 << 4));
        }

        float e_next = 0.0f;
        if (tid < CRF_K && t + 1 < CRF_T)
            e_next = emb[(t + 1) * CRF_K + tid];

        // quad-lane qi loads chunks {2qi, 2qi+1} of this wave's 32-prev
        // group: 2 per-lane b128 per wave (was 8 broadcast b128 per wave).
        // Wave addrs {0,32,64,96}(+16) -> banks {0,8,16,24}/{4,12,20,28},
        // conflict-free.
        const float4 sA = *(const float4*)(s_state + pbase + 8 * qi);
        const float4 sB = *(const float4*)(s_state + pbase + 8 * qi + 4);

        float m0 = -INFINITY, m1 = -INFINITY;
        FWD_CHUNK_Q(sA, 0, ta0, tb0) FWD_CHUNK_Q(sB, 0, ta1, tb1)
        FWD_CHUNK_Q(sA, 1, ta2, tb2) FWD_CHUNK_Q(sB, 1, ta3, tb3)
        FWD_CHUNK_Q(sA, 2, ta4, tb4) FWD_CHUNK_Q(sB, 2, ta5, tb5)
        FWD_CHUNK_Q(sA, 3, ta6, tb6) FWD_CHUNK_Q(sB, 3, ta7, tb7)

        s_partial[g][c]  = m0;
        s_partial[g][c2] = m1;
        __syncthreads();
        if (tid < CRF_K) {
            float p0 = s_partial[0][tid], p1 = s_partial[1][tid];
            float p2 = s_partial[2][tid], p3 = s_partial[3][tid];
            float p4 = s_partial[4][tid], p5 = s_partial[5][tid];
            float p6 = s_partial[6][tid], p7 = s_partial[7][tid];
            float q0 = fmaxf(fmaxf(p0, p1), p2);    // max3
            float q1 = fmaxf(fmaxf(p3, p4), p5);    // max3
            float bv = fmaxf(fmaxf(fmaxf(q0, q1), p6), p7);
            s_state[tid] = bv + e_cur;
            M[((size_t)t * CRF_B + b) * CRF_K + tid] = bv;   // PRE-emission
            sp0 = p0; sp1 = p1; sp2 = p2; sp3 = p3;
            sp4 = p4; sp5 = p5; sp6 = p6; sp7 = p7; sbv = bv;
        }
        __syncthreads();
        e_cur = e_next;
    }

    // flush gid for the final row (t = CRF_T-1)
    if (gidp && tid < CRF_K) {
        int bg = 7;
        if (sp6 == sbv) bg = 6;
        if (sp5 == sbv) bg = 5;
        if (sp4 == sbv) bg = 4;
        if (sp3 == sbv) bg = 3;
        if (sp2 == sbv) bg = 2;
        if (sp1 == sbv) bg = 1;
        if (sp0 == sbv) bg = 0;
        int g1 = __shfl_down(bg, 1, 64);
        if ((tid & 1) == 0)
            gidp[((size_t)(CRF_T - 1) * CRF_B + b) * 128 + (tid >> 1)] =
                (unsigned char)(bg | (g1 << 4));
    }
}

// ---------------------------------------------------------------------------
// bp via gid: 512 blocks (b x cg4 x ts2) x 256 thr (4 waves, t1 stride 4).
// 64KB transposed trans tile; gid byte for next iteration prefetched.
// ---------------------------------------------------------------------------

#define BPG_CHUNK(j) { \
    float4 mm = M4[j]; float4 ee = E4[j]; \
    float s0 = mm.x + ee.x, s1 = mm.y + ee.y; \
    float s2 = mm.z + ee.z, s3 = mm.w + ee.w; \
    float t0v = s_tile[base + 4*(j) + 0][lane]; \
    float t1v = s_tile[base + 4*(j) + 1][lane]; \
    float t2v = s_tile[base + 4*(j) + 2][lane]; \
    float t3v = s_tile[base + 4*(j) + 3][lane]; \
    float v0 = s0 + t0v; if (v0 > best) { best = v0; arg = base + 4*(j); } \
    float v1 = s1 + t1v; if (v1 > best) { best = v1; arg = base + 4*(j) + 1; } \
    float v2 = s2 + t2v; if (v2 > best) { best = v2; arg = base + 4*(j) + 2; } \
    float v3 = s3 + t3v; if (v3 > best) { best = v3; arg = base + 4*(j) + 3; } }

#define BPG_CHUNK0(j) { \
    float4 ee = E4[j]; \
    float t0v = s_tile[base + 4*(j) + 0][lane]; \
    float t1v = s_tile[base + 4*(j) + 1][lane]; \
    float t2v = s_tile[base + 4*(j) + 2][lane]; \
    float t3v = s_tile[base + 4*(j) + 3][lane]; \
    float v0 = ee.x + t0v; if (v0 > best) { best = v0; arg = base + 4*(j); } \
    float v1 = ee.y + t1v; if (v1 > best) { best = v1; arg = base + 4*(j) + 1; } \
    float v2 = ee.z + t2v; if (v2 > best) { best = v2; arg = base + 4*(j) + 2; } \
    float v3 = ee.w + t3v; if (v3 > best) { best = v3; arg = base + 4*(j) + 3; } }

__global__ __launch_bounds__(256) void crf_bp_gid(
    const float* __restrict__ M, const float* __restrict__ em,
    const float* __restrict__ trans, const unsigned char* __restrict__ gidp,
    unsigned char* __restrict__ bp)
{
    const int b    = blockIdx.x >> 3;
    const int cg   = (blockIdx.x >> 1) & 3;
    const int ts   = blockIdx.x & 1;
    const int tid  = threadIdx.x;
    const int lane = tid & 63;
    const int w    = tid >> 6;      // wave 0..3

    __shared__ float s_tile[CRF_K][64];   // 64 KB: s_tile[prev][col]

    const int k0 = cg * 64;
    for (int idx = tid; idx < CRF_K * 64; idx += 256) {
        const int p = idx >> 6, cc = idx & 63;
        s_tile[p][cc] = trans[(size_t)p * CRF_K + k0 + cc];
    }
    __syncthreads();

    const int t_lo = ts * 512;
    const int t_hi = ts ? (CRF_T - 1) : 512;
    const int half = (k0 >> 1) + (lane >> 1);
    const int odd  = lane & 1;

    int t1 = t_lo + w;
    if (t1 >= t_hi) return;
    unsigned char gb = gidp[((size_t)(t1 + 1) * CRF_B + b) * 128 + half];

    for (; t1 < t_hi; t1 += 4) {
        const int tn = t1 + 4;
        unsigned char gb_next = 0;
        if (tn < t_hi)                         // prefetch next gid byte
            gb_next = gidp[((size_t)(tn + 1) * CRF_B + b) * 128 + half];

        const int g    = odd ? ((gb >> 4) & 7) : (gb & 7);
        const int base = g << 5;
        const float4* E4 =
            (const float4*)(em + ((size_t)b * CRF_T + t1) * CRF_K + base);
        float best = -INFINITY; int arg = base;
        if (t1 == 0) {                         // state[0] = em[0]
            BPG_CHUNK0(0) BPG_CHUNK0(1) BPG_CHUNK0(2) BPG_CHUNK0(3)
            BPG_CHUNK0(4) BPG_CHUNK0(5) BPG_CHUNK0(6) BPG_CHUNK0(7)
        } else {
            const float4* M4 =
                (const float4*)(M + ((size_t)t1 * CRF_B + b) * CRF_K + base);
            BPG_CHUNK(0) BPG_CHUNK(1) BPG_CHUNK(2) BPG_CHUNK(3)
            BPG_CHUNK(4) BPG_CHUNK(5) BPG_CHUNK(6) BPG_CHUNK(7)
        }
        bp[((size_t)b * (CRF_T - 1) + t1) * CRF_K + k0 + lane] =
            (unsigned char)arg;
        gb = gb_next;
    }
}

// ---------------------------------------------------------------------------
// Fallback-B backpointers: full-scan bp_matrix (proven), state = M+em.
// ---------------------------------------------------------------------------

__global__ __launch_bounds__(1024, 2) void crf_bp_matrix(
    const float* __restrict__ M, const float* __restrict__ em,
    const float* __restrict__ trans, unsigned char* __restrict__ bp)
{
    const int b   = blockIdx.x >> 4;
    const int seg = blockIdx.x & 15;
    const int tid = threadIdx.x;
    const int g   = tid >> 8;      // 0..3
    const int k   = tid & 255;

    __shared__ __align__(16) float s_row[CRF_K];
    __shared__ float s_pv[4][CRF_K];
    __shared__ int   s_pi[4][CRF_K];

    const int pbase = g * 64;
    float4 tr[16];
#pragma unroll
    for (int i = 0; i < 16; ++i) {
        const int p = pbase + 4 * i;
        tr[i].x = trans[(p + 0) * CRF_K + k];
        tr[i].y = trans[(p + 1) * CRF_K + k];
        tr[i].z = trans[(p + 2) * CRF_K + k];
        tr[i].w = trans[(p + 3) * CRF_K + k];
    }

    const int t_lo = seg * SEGLEN;
    const int t_hi = min(t_lo + SEGLEN, CRF_T - 1);
    unsigned char* bpb = bp + (size_t)b * (CRF_T - 1) * CRF_K;

    for (int t1 = t_lo; t1 < t_hi; ++t1) {
        if (tid < CRF_K) {
            float ev = em[((size_t)b * CRF_T + t1) * CRF_K + tid];
            float sv = ev;
            if (t1 > 0) sv = M[((size_t)t1 * CRF_B + b) * CRF_K + tid] + ev;
            s_row[tid] = sv;
        }
        __syncthreads();

        float best = -INFINITY;
        int   arg  = pbase;
        const float4* spp = (const float4*)(s_row + pbase);
#pragma unroll
        for (int i = 0; i < 16; ++i) {
            float4 st = spp[i];
            const int p = pbase + 4 * i;
            float s0 = st.x + tr[i].x;
            float s1 = st.y + tr[i].y;
            float s2 = st.z + tr[i].z;
            float s3 = st.w + tr[i].w;
            if (s0 > best) { best = s0; arg = p; }
            if (s1 > best) { best = s1; arg = p + 1; }
            if (s2 > best) { best = s2; arg = p + 2; }
            if (s3 > best) { best = s3; arg = p + 3; }
        }
        s_pv[g][k] = best;
        s_pi[g][k] = arg;
        __syncthreads();
        if (tid < CRF_K) {
            float bv = s_pv[0][tid];
            int   ba = s_pi[0][tid];
#pragma unroll
            for (int j = 1; j < 4; ++j) {
                float v = s_pv[j][tid];
                if (v > bv) { bv = v; ba = s_pi[j][tid]; }
            }
            bpb[(size_t)t1 * CRF_K + tid] = (unsigned char)ba;
        }
        __syncthreads();
    }
}

// ---------------------------------------------------------------------------
// Segmented chase (proven): seg_maps -> compose -> emit.
// ---------------------------------------------------------------------------

__global__ __launch_bounds__(256) void crf_seg_maps(
    const unsigned char* __restrict__ bp, unsigned char* __restrict__ maps)
{
    const int b   = blockIdx.x >> 4;
    const int s   = blockIdx.x & 15;
    const int tid = threadIdx.x;
    const int rows = (s == NSEG - 1) ? SEGLEN - 1 : SEGLEN;
    const int r0   = s * SEGLEN;

    __shared__ unsigned char lbp[SEGLEN][CRF_K];   // 16 KB

    const unsigned char* bpb = bp + (size_t)b * (CRF_T - 1) * CRF_K;
    const int nw = rows * 64;
    for (int w = tid; w < nw; w += 256) {
        const int r = w >> 6, cc = w & 63;
        ((unsigned int*)lbp[r])[cc] =
            ((const unsigned int*)(bpb + (size_t)(r0 + r) * CRF_K))[cc];
    }
    __syncthreads();

    int tag = tid;
    for (int j = rows - 1; j >= 0; --j) tag = lbp[j][tag];
    maps[((size_t)b * NSEG + s) * CRF_K + tid] = (unsigned char)tag;
}

__global__ __launch_bounds__(256) void crf_compose(
    const float* __restrict__ M, const float* __restrict__ em,
    const unsigned char* __restrict__ maps,
    int* __restrict__ exits, float* __restrict__ out)
{
    const int b   = blockIdx.x;
    const int tid = threadIdx.x;

    __shared__ float s_wv[4];
    __shared__ int   s_wi[4];

    float v = M[((size_t)(CRF_T - 1) * CRF_B + b) * CRF_K + tid]
            + em[((size_t)b * CRF_T + (CRF_T - 1)) * CRF_K + tid];
    int   i = tid;
#pragma unroll
    for (int off = 32; off >= 1; off >>= 1) {
        float ov = __shfl_xor(v, off, 64);
        int   oi = __shfl_xor(i, off, 64);
        if (ov > v || (ov == v && oi < i)) { v = ov; i = oi; }
    }
    const int lane = tid & 63, wv = tid >> 6;
    if (lane == 0) { s_wv[wv] = v; s_wi[wv] = i; }
    __syncthreads();
    if (tid == 0) {
        float bv = s_wv[0]; int bi = s_wi[0];
#pragma unroll
        for (int w = 1; w < 4; ++w)
            if (s_wv[w] > bv) { bv = s_wv[w]; bi = s_wi[w]; }
        out[(size_t)b * CRF_T + (CRF_T - 1)] = (float)bi;
        int E = bi;
        exits[b * NSEG + NSEG - 1] = E;
        const unsigned char* mb = maps + (size_t)b * NSEG * CRF_K;
        for (int s = NSEG - 1; s >= 1; --s) {
            E = mb[(size_t)s * CRF_K + E];
            exits[b * NSEG + s - 1] = E;
        }
    }
}

__global__ __launch_bounds__(256) void crf_emit(
    const unsigned char* __restrict__ bp, const int* __restrict__ exits,
    float* __restrict__ out)
{
    const int b   = blockIdx.x >> 4;
    const int s   = blockIdx.x & 15;
    const int tid = threadIdx.x;
    const int rows = (s == NSEG - 1) ? SEGLEN - 1 : SEGLEN;
    const int r0   = s * SEGLEN;

    __shared__ unsigned char lbp[SEGLEN][CRF_K];

    const unsigned char* bpb = bp + (size_t)b * (CRF_T - 1) * CRF_K;
    const int nw = rows * 64;
    for (int w = tid; w < nw; w += 256) {
        const int r = w >> 6, cc = w & 63;
        ((unsigned int*)lbp[r])[cc] =
            ((const unsigned int*)(bpb + (size_t)(r0 + r) * CRF_K))[cc];
    }
    __syncthreads();

    int tag = tid;
    const bool win = (tid == exits[b * NSEG + s]);
    for (int j = rows - 1; j >= 0; --j) {
        tag = lbp[j][tag];
        if (win) out[(size_t)b * CRF_T + r0 + j] = (float)tag;
    }
}

__global__ void crf_zero_out(float* __restrict__ out, int n)
{
    int i = blockIdx.x * blockDim.x + threadIdx.x;
    if (i < n) out[i] = 0.0f;
}

// ---------------------------------------------------------------------------

extern "C" void kernel_launch(void* const* d_in, const int* in_sizes, int n_in,
                              void* d_out, int out_size, void* d_ws, size_t ws_size,
                              hipStream_t stream) {
    (void)in_sizes; (void)n_in;
    const float* em    = (const float*)d_in[0];   // [B,T,K]
    const float* trans = (const float*)d_in[1];   // [K,K]
    float* out = (float*)d_out;                   // [B,T]

    const size_t M_bytes     = (size_t)CRF_T * CRF_B * CRF_K * sizeof(float); // 64 MB
    const size_t gid_bytes   = (size_t)CRF_T * CRF_B * 128;                   // 8.4 MB
    const size_t bp_bytes    = (size_t)CRF_B * (CRF_T - 1) * CRF_K;           // 16.75 MB
    const size_t maps_bytes  = (size_t)CRF_B * NSEG * CRF_K;                  // 256 KB
    const size_t exits_bytes = (size_t)CRF_B * NSEG * sizeof(int);            // 4 KB

    char* w = (char*)d_ws;
    if (ws_size >= M_bytes + gid_bytes + bp_bytes + maps_bytes + exits_bytes) {
        float*         M     = (float*)w;            w += M_bytes;
        unsigned char* gidp  = (unsigned char*)w;    w += gid_bytes;
        unsigned char* bp    = (unsigned char*)w;    w += bp_bytes;
        unsigned char* maps  = (unsigned char*)w;    w += maps_bytes;
        int*           exits = (int*)w;

        crf_forward_states<<<CRF_B, 1024, 0, stream>>>(em, trans, M, gidp);
        crf_bp_gid<<<CRF_B * 8, 256, 0, stream>>>(M, em, trans, gidp, bp);
        crf_seg_maps<<<CRF_B * NSEG, 256, 0, stream>>>(bp, maps);
        crf_compose<<<CRF_B, 256, 0, stream>>>(M, em, maps, exits, out);
        crf_emit<<<CRF_B * NSEG, 256, 0, stream>>>(bp, exits, out);
    } else if (ws_size >= M_bytes + bp_bytes + maps_bytes + exits_bytes) {
        float*         M     = (float*)w;            w += M_bytes;
        unsigned char* bp    = (unsigned char*)w;    w += bp_bytes;
        unsigned char* maps  = (unsigned char*)w;    w += maps_bytes;
        int*           exits = (int*)w;

        crf_forward_states<<<CRF_B, 1024, 0, stream>>>(em, trans, M, nullptr);
        crf_bp_matrix<<<CRF_B * NSEG, 1024, 0, stream>>>(M, em, trans, bp);
        crf_seg_maps<<<CRF_B * NSEG, 256, 0, stream>>>(bp, maps);
        crf_compose<<<CRF_B, 256, 0, stream>>>(M, em, maps, exits, out);
        crf_emit<<<CRF_B * NSEG, 256, 0, stream>>>(bp, exits, out);
    } else {
        crf_zero_out<<<(out_size + 255) / 256, 256, 0, stream>>>(out, out_size);
    }
}

// Round 6
// 1233.217 us; speedup vs baseline: 1.4186x; 1.0237x over previous
//
#include <hip/hip_runtime.h>

// CRF Viterbi decode: B=64, T=1024, K=256.
// emissions [B,T,K] f32, transitions [K,K] f32 (prev->next). out [B,T] f32 tags.
//
// Model (r0-r5 evidence): forward is VALU-ISSUE-bound, NOT LDS-bound.
// r0: 90% VALU-issue occupancy at ~215 instr/wave/step (1912 cyc/step).
// r5 halved LDS instrs -> time UP (2301) => broadcasts were cheap all along;
// per-lane+DPP redesigns (r1/r4/r5) lost to stalls (65-74% occupancy).
// r6: keep r0's proven phase-1 (broadcast b128 chunk reads, AGPR-resident
// trans, max3-shaped compute) and cut the OTHER ~115 instrs:
//   - reducer+gid: was waves 0-3 serial (12 waves idle) with deferred-gid
//     register carry; now ALL-wave quad-parallel: s_partial transposed to
//     [col][9] (pad 9 = conflict-free writes AND reads), col=tid>>2, quad
//     lane j reads partials {2j,2j+1} (two b32, parity blocks b64 fusion),
//     2 DPP quad_perm max hops (xor1/xor2, proven in r3/r4) -> bv on all 4
//     lanes; gid = ffs(quad-ORed equality mask) = same lowest-group
//     semantics as r0's if-chain; 9 deferred-gid regs deleted.
//   - all global pointers increment (r0 re-derived 64b addrs each iter).
// Values bit-identical (same adds, same fmax tree, exact-equality gid) ->
// bp_gid / seg_maps / compose / emit untouched.
//
// Path A: forward -> bp_gid -> seg_maps -> compose -> emit.
// Path B: forward(no gid) + bp_matrix full scan + chase.  Path C: zero.

#define CRF_B 64
#define CRF_T 1024
#define CRF_K 256
#define NSEG  16
#define SEGLEN 64

#define FG 8
#define FP 32
#define PPAD 9

// ---------------------------------------------------------------------------
// Forward
// ---------------------------------------------------------------------------

#define LD4(v, p, col) { \
    v.x = trans[(size_t)(p) * CRF_K + (col)]; \
    v.y = trans[(size_t)((p) + 1) * CRF_K + (col)]; \
    v.z = trans[(size_t)((p) + 2) * CRF_K + (col)]; \
    v.w = trans[(size_t)((p) + 3) * CRF_K + (col)]; }

// max3-shaped: fmaxf(fmaxf(x,y),z) fuses to v_max3_f32
#define FWD_CHUNK(idx, ta, tb) { \
    float4 sv = sp[idx]; \
    float a0 = sv.x + ta.x; \
    float a1 = sv.y + ta.y; \
    float a2 = sv.z + ta.z; \
    float a3 = sv.w + ta.w; \
    float r0 = fmaxf(fmaxf(a0, a1), a2); \
    m0 = fmaxf(fmaxf(r0, a3), m0); \
    float c0 = sv.x + tb.x; \
    float c1 = sv.y + tb.y; \
    float c2 = sv.z + tb.z; \
    float c3 = sv.w + tb.w; \
    float r1 = fmaxf(fmaxf(c0, c1), c2); \
    m1 = fmaxf(fmaxf(r1, c3), m1); }

#define DPP_QP_XOR1 0xB1   // quad_perm [1,0,3,2]
#define DPP_QP_XOR2 0x4E   // quad_perm [2,3,0,1]

template <int CTRL>
__device__ __forceinline__ float dpp_getf(float v) {
    return __int_as_float(__builtin_amdgcn_update_dpp(
        0, __float_as_int(v), CTRL, 0xf, 0xf, false));
}
template <int CTRL>
__device__ __forceinline__ int dpp_geti(int v) {
    return __builtin_amdgcn_update_dpp(0, v, CTRL, 0xf, 0xf, false);
}

__global__ __launch_bounds__(1024, 4) void crf_forward_states(
    const float* __restrict__ em, const float* __restrict__ trans,
    float* __restrict__ M, unsigned char* __restrict__ gidp)
{
    const int b   = blockIdx.x;
    const int tid = threadIdx.x;
    const int g   = tid >> 7;      // phase-1 prev group 0..7
    const int c   = tid & 127;     // phase-1 columns c and c+128
    const int col = tid >> 2;      // phase-3 owned column
    const int j   = tid & 3;       // phase-3 quad lane

    __shared__ __align__(16) float s_state[CRF_K];
    __shared__ float s_partial[CRF_K][PPAD];   // [col][g], pad 9

    const int pbase = g * FP;
    const int c2    = c + 128;

    float4 ta0, ta1, ta2, ta3, ta4, ta5, ta6, ta7;
    float4 tb0, tb1, tb2, tb3, tb4, tb5, tb6, tb7;
    LD4(ta0, pbase +  0, c)  LD4(ta1, pbase +  4, c)
    LD4(ta2, pbase +  8, c)  LD4(ta3, pbase + 12, c)
    LD4(ta4, pbase + 16, c)  LD4(ta5, pbase + 20, c)
    LD4(ta6, pbase + 24, c)  LD4(ta7, pbase + 28, c)
    LD4(tb0, pbase +  0, c2) LD4(tb1, pbase +  4, c2)
    LD4(tb2, pbase +  8, c2) LD4(tb3, pbase + 12, c2)
    LD4(tb4, pbase + 16, c2) LD4(tb5, pbase + 20, c2)
    LD4(tb6, pbase + 24, c2) LD4(tb7, pbase + 28, c2)

    const float* emb = em + (size_t)b * CRF_T * CRF_K;
    if (tid < CRF_K) s_state[tid] = emb[tid];          // state[0] = em[0]
    float e_cur = emb[CRF_K + col];                    // em[1][col], all lanes
    __syncthreads();

    // pointer-increment state (no per-iter 64b addr derivation)
    float* mp = M + ((size_t)CRF_B + b) * CRF_K + col;              // row t=1
    unsigned char* gp = gidp
        ? gidp + ((size_t)CRF_B + b) * 128 + (col >> 1)             // row t=1
        : nullptr;
    const float* ep = emb + 2 * CRF_K + col;                        // em[t+1]

    for (int t = 1; t < CRF_T; ++t) {
        float e_next = 0.0f;
        if (t + 1 < CRF_T) e_next = *ep;

        // ---- phase 1: chunk compute (proven r0 body) ----
        float m0 = -INFINITY, m1 = -INFINITY;
        const float4* sp = (const float4*)(s_state + pbase);
        FWD_CHUNK(0, ta0, tb0) FWD_CHUNK(1, ta1, tb1)
        FWD_CHUNK(2, ta2, tb2) FWD_CHUNK(3, ta3, tb3)
        FWD_CHUNK(4, ta4, tb4) FWD_CHUNK(5, ta5, tb5)
        FWD_CHUNK(6, ta6, tb6) FWD_CHUNK(7, ta7, tb7)

        s_partial[c][g]  = m0;      // addr 9c+g: 2 lanes/bank, free
        s_partial[c2][g] = m1;
        __syncthreads();

        // ---- phase 3: all-wave quad reduce (4 lanes per column) ----
        const float px = s_partial[col][2 * j];      // parity-odd base:
        const float py = s_partial[col][2 * j + 1];  // stays b32, no b64
        float mm = fmaxf(px, py);
        mm = fmaxf(mm, dpp_getf<DPP_QP_XOR1>(mm));
        const float bv = fmaxf(mm, dpp_getf<DPP_QP_XOR2>(mm)); // all 4 lanes

        if (j == 0) {
            *mp = bv;                                // M = PRE-emission max
            s_state[col] = bv + e_cur;
        }
        mp += CRF_B * CRF_K;

        if (gp) {
            int mk = 0;
            if (px == bv) mk  = 1 << (2 * j);
            if (py == bv) mk |= 1 << (2 * j + 1);
            mk |= dpp_geti<DPP_QP_XOR1>(mk);
            mk |= dpp_geti<DPP_QP_XOR2>(mk);         // 8-bit group mask
            const int gv = __ffs(mk) - 1;            // lowest matching group
            const int go = __shfl_down(gv, 4, 64);   // gid of col+1
            if ((tid & 7) == 0)
                *gp = (unsigned char)(gv | (go << 4));
            gp += CRF_B * 128;
        }

        __syncthreads();
        e_cur = e_next;
        ep += CRF_K;
    }
}

// ---------------------------------------------------------------------------
// bp via gid: 512 blocks (b x cg4 x ts2) x 256 thr (4 waves, t1 stride 4).
// 64KB transposed trans tile; gid byte for next iteration prefetched.
// ---------------------------------------------------------------------------

#define BPG_CHUNK(j) { \
    float4 mm = M4[j]; float4 ee = E4[j]; \
    float s0 = mm.x + ee.x, s1 = mm.y + ee.y; \
    float s2 = mm.z + ee.z, s3 = mm.w + ee.w; \
    float t0v = s_tile[base + 4*(j) + 0][lane]; \
    float t1v = s_tile[base + 4*(j) + 1][lane]; \
    float t2v = s_tile[base + 4*(j) + 2][lane]; \
    float t3v = s_tile[base + 4*(j) + 3][lane]; \
    float v0 = s0 + t0v; if (v0 > best) { best = v0; arg = base + 4*(j); } \
    float v1 = s1 + t1v; if (v1 > best) { best = v1; arg = base + 4*(j) + 1; } \
    float v2 = s2 + t2v; if (v2 > best) { best = v2; arg = base + 4*(j) + 2; } \
    float v3 = s3 + t3v; if (v3 > best) { best = v3; arg = base + 4*(j) + 3; } }

#define BPG_CHUNK0(j) { \
    float4 ee = E4[j]; \
    float t0v = s_tile[base + 4*(j) + 0][lane]; \
    float t1v = s_tile[base + 4*(j) + 1][lane]; \
    float t2v = s_tile[base + 4*(j) + 2][lane]; \
    float t3v = s_tile[base + 4*(j) + 3][lane]; \
    float v0 = ee.x + t0v; if (v0 > best) { best = v0; arg = base + 4*(j); } \
    float v1 = ee.y + t1v; if (v1 > best) { best = v1; arg = base + 4*(j) + 1; } \
    float v2 = ee.z + t2v; if (v2 > best) { best = v2; arg = base + 4*(j) + 2; } \
    float v3 = ee.w + t3v; if (v3 > best) { best = v3; arg = base + 4*(j) + 3; } }

__global__ __launch_bounds__(256) void crf_bp_gid(
    const float* __restrict__ M, const float* __restrict__ em,
    const float* __restrict__ trans, const unsigned char* __restrict__ gidp,
    unsigned char* __restrict__ bp)
{
    const int b    = blockIdx.x >> 3;
    const int cg   = (blockIdx.x >> 1) & 3;
    const int ts   = blockIdx.x & 1;
    const int tid  = threadIdx.x;
    const int lane = tid & 63;
    const int w    = tid >> 6;      // wave 0..3

    __shared__ float s_tile[CRF_K][64];   // 64 KB: s_tile[prev][col]

    const int k0 = cg * 64;
    for (int idx = tid; idx < CRF_K * 64; idx += 256) {
        const int p = idx >> 6, cc = idx & 63;
        s_tile[p][cc] = trans[(size_t)p * CRF_K + k0 + cc];
    }
    __syncthreads();

    const int t_lo = ts * 512;
    const int t_hi = ts ? (CRF_T - 1) : 512;
    const int half = (k0 >> 1) + (lane >> 1);
    const int odd  = lane & 1;

    int t1 = t_lo + w;
    if (t1 >= t_hi) return;
    unsigned char gb = gidp[((size_t)(t1 + 1) * CRF_B + b) * 128 + half];

    for (; t1 < t_hi; t1 += 4) {
        const int tn = t1 + 4;
        unsigned char gb_next = 0;
        if (tn < t_hi)                         // prefetch next gid byte
            gb_next = gidp[((size_t)(tn + 1) * CRF_B + b) * 128 + half];

        const int g    = odd ? ((gb >> 4) & 7) : (gb & 7);
        const int base = g << 5;
        const float4* E4 =
            (const float4*)(em + ((size_t)b * CRF_T + t1) * CRF_K + base);
        float best = -INFINITY; int arg = base;
        if (t1 == 0) {                         // state[0] = em[0]
            BPG_CHUNK0(0) BPG_CHUNK0(1) BPG_CHUNK0(2) BPG_CHUNK0(3)
            BPG_CHUNK0(4) BPG_CHUNK0(5) BPG_CHUNK0(6) BPG_CHUNK0(7)
        } else {
            const float4* M4 =
                (const float4*)(M + ((size_t)t1 * CRF_B + b) * CRF_K + base);
            BPG_CHUNK(0) BPG_CHUNK(1) BPG_CHUNK(2) BPG_CHUNK(3)
            BPG_CHUNK(4) BPG_CHUNK(5) BPG_CHUNK(6) BPG_CHUNK(7)
        }
        bp[((size_t)b * (CRF_T - 1) + t1) * CRF_K + k0 + lane] =
            (unsigned char)arg;
        gb = gb_next;
    }
}

// ---------------------------------------------------------------------------
// Fallback-B backpointers: full-scan bp_matrix (proven), state = M+em.
// ---------------------------------------------------------------------------

__global__ __launch_bounds__(1024, 2) void crf_bp_matrix(
    const float* __restrict__ M, const float* __restrict__ em,
    const float* __restrict__ trans, unsigned char* __restrict__ bp)
{
    const int b   = blockIdx.x >> 4;
    const int seg = blockIdx.x & 15;
    const int tid = threadIdx.x;
    const int g   = tid >> 8;      // 0..3
    const int k   = tid & 255;

    __shared__ __align__(16) float s_row[CRF_K];
    __shared__ float s_pv[4][CRF_K];
    __shared__ int   s_pi[4][CRF_K];

    const int pbase = g * 64;
    float4 tr[16];
#pragma unroll
    for (int i = 0; i < 16; ++i) {
        const int p = pbase + 4 * i;
        tr[i].x = trans[(p + 0) * CRF_K + k];
        tr[i].y = trans[(p + 1) * CRF_K + k];
        tr[i].z = trans[(p + 2) * CRF_K + k];
        tr[i].w = trans[(p + 3) * CRF_K + k];
    }

    const int t_lo = seg * SEGLEN;
    const int t_hi = min(t_lo + SEGLEN, CRF_T - 1);
    unsigned char* bpb = bp + (size_t)b * (CRF_T - 1) * CRF_K;

    for (int t1 = t_lo; t1 < t_hi; ++t1) {
        if (tid < CRF_K) {
            float ev = em[((size_t)b * CRF_T + t1) * CRF_K + tid];
            float sv = ev;
            if (t1 > 0) sv = M[((size_t)t1 * CRF_B + b) * CRF_K + tid] + ev;
            s_row[tid] = sv;
        }
        __syncthreads();

        float best = -INFINITY;
        int   arg  = pbase;
        const float4* spp = (const float4*)(s_row + pbase);
#pragma unroll
        for (int i = 0; i < 16; ++i) {
            float4 st = spp[i];
            const int p = pbase + 4 * i;
            float s0 = st.x + tr[i].x;
            float s1 = st.y + tr[i].y;
            float s2 = st.z + tr[i].z;
            float s3 = st.w + tr[i].w;
            if (s0 > best) { best = s0; arg = p; }
            if (s1 > best) { best = s1; arg = p + 1; }
            if (s2 > best) { best = s2; arg = p + 2; }
            if (s3 > best) { best = s3; arg = p + 3; }
        }
        s_pv[g][k] = best;
        s_pi[g][k] = arg;
        __syncthreads();
        if (tid < CRF_K) {
            float bv = s_pv[0][tid];
            int   ba = s_pi[0][tid];
#pragma unroll
            for (int j = 1; j < 4; ++j) {
                float v = s_pv[j][tid];
                if (v > bv) { bv = v; ba = s_pi[j][tid]; }
            }
            bpb[(size_t)t1 * CRF_K + tid] = (unsigned char)ba;
        }
        __syncthreads();
    }
}

// ---------------------------------------------------------------------------
// Segmented chase (proven): seg_maps -> compose -> emit.
// ---------------------------------------------------------------------------

__global__ __launch_bounds__(256) void crf_seg_maps(
    const unsigned char* __restrict__ bp, unsigned char* __restrict__ maps)
{
    const int b   = blockIdx.x >> 4;
    const int s   = blockIdx.x & 15;
    const int tid = threadIdx.x;
    const int rows = (s == NSEG - 1) ? SEGLEN - 1 : SEGLEN;
    const int r0   = s * SEGLEN;

    __shared__ unsigned char lbp[SEGLEN][CRF_K];   // 16 KB

    const unsigned char* bpb = bp + (size_t)b * (CRF_T - 1) * CRF_K;
    const int nw = rows * 64;
    for (int w = tid; w < nw; w += 256) {
        const int r = w >> 6, cc = w & 63;
        ((unsigned int*)lbp[r])[cc] =
            ((const unsigned int*)(bpb + (size_t)(r0 + r) * CRF_K))[cc];
    }
    __syncthreads();

    int tag = tid;
    for (int j = rows - 1; j >= 0; --j) tag = lbp[j][tag];
    maps[((size_t)b * NSEG + s) * CRF_K + tid] = (unsigned char)tag;
}

__global__ __launch_bounds__(256) void crf_compose(
    const float* __restrict__ M, const float* __restrict__ em,
    const unsigned char* __restrict__ maps,
    int* __restrict__ exits, float* __restrict__ out)
{
    const int b   = blockIdx.x;
    const int tid = threadIdx.x;

    __shared__ float s_wv[4];
    __shared__ int   s_wi[4];

    float v = M[((size_t)(CRF_T - 1) * CRF_B + b) * CRF_K + tid]
            + em[((size_t)b * CRF_T + (CRF_T - 1)) * CRF_K + tid];
    int   i = tid;
#pragma unroll
    for (int off = 32; off >= 1; off >>= 1) {
        float ov = __shfl_xor(v, off, 64);
        int   oi = __shfl_xor(i, off, 64);
        if (ov > v || (ov == v && oi < i)) { v = ov; i = oi; }
    }
    const int lane = tid & 63, wv = tid >> 6;
    if (lane == 0) { s_wv[wv] = v; s_wi[wv] = i; }
    __syncthreads();
    if (tid == 0) {
        float bv = s_wv[0]; int bi = s_wi[0];
#pragma unroll
        for (int w = 1; w < 4; ++w)
            if (s_wv[w] > bv) { bv = s_wv[w]; bi = s_wi[w]; }
        out[(size_t)b * CRF_T + (CRF_T - 1)] = (float)bi;
        int E = bi;
        exits[b * NSEG + NSEG - 1] = E;
        const unsigned char* mb = maps + (size_t)b * NSEG * CRF_K;
        for (int s = NSEG - 1; s >= 1; --s) {
            E = mb[(size_t)s * CRF_K + E];
            exits[b * NSEG + s - 1] = E;
        }
    }
}

__global__ __launch_bounds__(256) void crf_emit(
    const unsigned char* __restrict__ bp, const int* __restrict__ exits,
    float* __restrict__ out)
{
    const int b   = blockIdx.x >> 4;
    const int s   = blockIdx.x & 15;
    const int tid = threadIdx.x;
    const int rows = (s == NSEG - 1) ? SEGLEN - 1 : SEGLEN;
    const int r0   = s * SEGLEN;

    __shared__ unsigned char lbp[SEGLEN][CRF_K];

    const unsigned char* bpb = bp + (size_t)b * (CRF_T - 1) * CRF_K;
    const int nw = rows * 64;
    for (int w = tid; w < nw; w += 256) {
        const int r = w >> 6, cc = w & 63;
        ((unsigned int*)lbp[r])[cc] =
            ((const unsigned int*)(bpb + (size_t)(r0 + r) * CRF_K))[cc];
    }
    __syncthreads();

    int tag = tid;
    const bool win = (tid == exits[b * NSEG + s]);
    for (int j = rows - 1; j >= 0; --j) {
        tag = lbp[j][tag];
        if (win) out[(size_t)b * CRF_T + r0 + j] = (float)tag;
    }
}

__global__ void crf_zero_out(float* __restrict__ out, int n)
{
    int i = blockIdx.x * blockDim.x + threadIdx.x;
    if (i < n) out[i] = 0.0f;
}

// ---------------------------------------------------------------------------

extern "C" void kernel_launch(void* const* d_in, const int* in_sizes, int n_in,
                              void* d_out, int out_size, void* d_ws, size_t ws_size,
                              hipStream_t stream) {
    (void)in_sizes; (void)n_in;
    const float* em    = (const float*)d_in[0];   // [B,T,K]
    const float* trans = (const float*)d_in[1];   // [K,K]
    float* out = (float*)d_out;                   // [B,T]

    const size_t M_bytes     = (size_t)CRF_T * CRF_B * CRF_K * sizeof(float); // 64 MB
    const size_t gid_bytes   = (size_t)CRF_T * CRF_B * 128;                   // 8.4 MB
    const size_t bp_bytes    = (size_t)CRF_B * (CRF_T - 1) * CRF_K;           // 16.75 MB
    const size_t maps_bytes  = (size_t)CRF_B * NSEG * CRF_K;                  // 256 KB
    const size_t exits_bytes = (size_t)CRF_B * NSEG * sizeof(int);            // 4 KB

    char* w = (char*)d_ws;
    if (ws_size >= M_bytes + gid_bytes + bp_bytes + maps_bytes + exits_bytes) {
        float*         M     = (float*)w;            w += M_bytes;
        unsigned char* gidp  = (unsigned char*)w;    w += gid_bytes;
        unsigned char* bp    = (unsigned char*)w;    w += bp_bytes;
        unsigned char* maps  = (unsigned char*)w;    w += maps_bytes;
        int*           exits = (int*)w;

        crf_forward_states<<<CRF_B, 1024, 0, stream>>>(em, trans, M, gidp);
        crf_bp_gid<<<CRF_B * 8, 256, 0, stream>>>(M, em, trans, gidp, bp);
        crf_seg_maps<<<CRF_B * NSEG, 256, 0, stream>>>(bp, maps);
        crf_compose<<<CRF_B, 256, 0, stream>>>(M, em, maps, exits, out);
        crf_emit<<<CRF_B * NSEG, 256, 0, stream>>>(bp, exits, out);
    } else if (ws_size >= M_bytes + bp_bytes + maps_bytes + exits_bytes) {
        float*         M     = (float*)w;            w += M_bytes;
        unsigned char* bp    = (unsigned char*)w;    w += bp_bytes;
        unsigned char* maps  = (unsigned char*)w;    w += maps_bytes;
        int*           exits = (int*)w;

        crf_forward_states<<<CRF_B, 1024, 0, stream>>>(em, trans, M, nullptr);
        crf_bp_matrix<<<CRF_B * NSEG, 1024, 0, stream>>>(M, em, trans, bp);
        crf_seg_maps<<<CRF_B * NSEG, 256, 0, stream>>>(bp, maps);
        crf_compose<<<CRF_B, 256, 0, stream>>>(M, em, maps, exits, out);
        crf_emit<<<CRF_B * NSEG, 256, 0, stream>>>(bp, exits, out);
    } else {
        crf_zero_out<<<(out_size + 255) / 256, 256, 0, stream>>>(out, out_size);
    }
}

// Round 7
// 1107.030 us; speedup vs baseline: 1.5804x; 1.1140x over previous
//
#include <hip/hip_runtime.h>

// CRF Viterbi decode: B=64, T=1024, K=256.
// emissions [B,T,K] f32, transitions [K,K] f32 (prev->next). out [B,T] f32 tags.
//
// Model (r0-r6): forward is VALU-ISSUE-bound at ~90% issue occupancy; time
// tracks instrs/wave/step (r0: 215 -> 1912 cyc/step; r6: 253 -> 2243).
// Structural redesigns (per-lane state r1, DPP butterfly r3/r4, quad-share
// r5, all-wave reduce r6) all ADDED per-wave instructions or stalls and
// lost. r0's 2-phase structure (broadcast b128 state reads, AGPR-resident
// trans, 4-wave serial reducer whose cost is hidden behind the barrier at
// 90% occupancy, deferred gid) is kept VERBATIM.
//
// r7 single-variable change: phase-1 chunk adds 8 scalar v_add_f32 ->
// 4 v_pk_add_f32 via native ext_vector f32x2 (+) (r3 proved asm-"v"
// constraints poison AGPR codegen; r4 proved the native form compiles
// clean). State pairs (sv.x,sv.y)/(sv.z,sv.w) come from ds_read_b128's
// consecutive VGPRs (VOP3P-aligned); trans fragments stored as f32x2
// pairs. Identical IEEE adds + identical max3 tree -> bit-exact; gid /
// bp_gid / seg_maps / compose / emit untouched.
// Phase-1 core: 96 -> 64 instrs/wave/step; projected ~183 total (-15%).
//
// Path A: forward -> bp_gid -> seg_maps -> compose -> emit.
// Path B: forward(no gid) + bp_matrix full scan + chase.  Path C: zero.

#define CRF_B 64
#define CRF_T 1024
#define CRF_K 256
#define NSEG  16
#define SEGLEN 64

#define FG 8
#define FP 32

// ---------------------------------------------------------------------------
// Forward
// ---------------------------------------------------------------------------

typedef float f32x2 __attribute__((ext_vector_type(2)));

// load trans[p..p+3][col] as two f32x2 pairs
#define LD22(v01, v23, p, col) { \
    v01.x = trans[(size_t)(p) * CRF_K + (col)]; \
    v01.y = trans[(size_t)((p) + 1) * CRF_K + (col)]; \
    v23.x = trans[(size_t)((p) + 2) * CRF_K + (col)]; \
    v23.y = trans[(size_t)((p) + 3) * CRF_K + (col)]; }

// 4 v_pk_add_f32 + 4 max3-shaped fmax per chunk (was 8 add + 4 max3).
// fmaxf(fmaxf(x,y),z) fuses to v_max3_f32.
#define FWD_CHUNK(idx, A01, A23, B01, B23) { \
    float4 sv = sp[idx]; \
    f32x2 s01; s01.x = sv.x; s01.y = sv.y; \
    f32x2 s23; s23.x = sv.z; s23.y = sv.w; \
    f32x2 a01 = s01 + A01; \
    f32x2 a23 = s23 + A23; \
    float r0 = fmaxf(fmaxf(a01.x, a01.y), a23.x); \
    m0 = fmaxf(fmaxf(r0, a23.y), m0); \
    f32x2 c01 = s01 + B01; \
    f32x2 c23 = s23 + B23; \
    float r1 = fmaxf(fmaxf(c01.x, c01.y), c23.x); \
    m1 = fmaxf(fmaxf(r1, c23.y), m1); }

__global__ __launch_bounds__(1024, 4) void crf_forward_states(
    const float* __restrict__ em, const float* __restrict__ trans,
    float* __restrict__ M, unsigned char* __restrict__ gidp)
{
    const int b   = blockIdx.x;
    const int tid = threadIdx.x;
    const int g   = tid >> 7;      // prev group 0..7
    const int c   = tid & 127;     // columns c and c+128

    __shared__ __align__(16) float s_state[CRF_K];
    __shared__ float s_partial[FG][CRF_K];

    const int pbase = g * FP;
    const int c2    = c + 128;

    f32x2 ta01_0, ta23_0, ta01_1, ta23_1, ta01_2, ta23_2, ta01_3, ta23_3;
    f32x2 ta01_4, ta23_4, ta01_5, ta23_5, ta01_6, ta23_6, ta01_7, ta23_7;
    f32x2 tb01_0, tb23_0, tb01_1, tb23_1, tb01_2, tb23_2, tb01_3, tb23_3;
    f32x2 tb01_4, tb23_4, tb01_5, tb23_5, tb01_6, tb23_6, tb01_7, tb23_7;
    LD22(ta01_0, ta23_0, pbase +  0, c)  LD22(ta01_1, ta23_1, pbase +  4, c)
    LD22(ta01_2, ta23_2, pbase +  8, c)  LD22(ta01_3, ta23_3, pbase + 12, c)
    LD22(ta01_4, ta23_4, pbase + 16, c)  LD22(ta01_5, ta23_5, pbase + 20, c)
    LD22(ta01_6, ta23_6, pbase + 24, c)  LD22(ta01_7, ta23_7, pbase + 28, c)
    LD22(tb01_0, tb23_0, pbase +  0, c2) LD22(tb01_1, tb23_1, pbase +  4, c2)
    LD22(tb01_2, tb23_2, pbase +  8, c2) LD22(tb01_3, tb23_3, pbase + 12, c2)
    LD22(tb01_4, tb23_4, pbase + 16, c2) LD22(tb01_5, tb23_5, pbase + 20, c2)
    LD22(tb01_6, tb23_6, pbase + 24, c2) LD22(tb01_7, tb23_7, pbase + 28, c2)

    const float* emb = em + (size_t)b * CRF_T * CRF_K;
    if (tid < CRF_K) s_state[tid] = emb[tid];          // state[0] = em[0]
    float e_cur = 0.0f;
    if (tid < CRF_K) e_cur = emb[CRF_K + tid];         // emission for t = 1
    __syncthreads();

    // deferred-gid state (saved across the barrier; stored one step later)
    float sp0 = 0, sp1 = 0, sp2 = 0, sp3 = 0;
    float sp4 = 0, sp5 = 0, sp6 = 0, sp7 = 0;
    float sbv = 0;

    for (int t = 1; t < CRF_T; ++t) {
        // deferred gid store for step t-1 (reads saved regs only; overlaps
        // all waves' chunk compute instead of the serial reducer section)
        if (gidp && tid < CRF_K && t > 1) {
            int bg = 7;
            if (sp6 == sbv) bg = 6;
            if (sp5 == sbv) bg = 5;
            if (sp4 == sbv) bg = 4;
            if (sp3 == sbv) bg = 3;
            if (sp2 == sbv) bg = 2;
            if (sp1 == sbv) bg = 1;
            if (sp0 == sbv) bg = 0;
            int g1 = __shfl_down(bg, 1, 64);
            if ((tid & 1) == 0)
                gidp[((size_t)(t - 1) * CRF_B + b) * 128 + (tid >> 1)] =
                    (unsigned char)(bg | (g1 << 4));
        }

        float e_next = 0.0f;
        if (tid < CRF_K && t + 1 < CRF_T)
            e_next = emb[(t + 1) * CRF_K + tid];

        float m0 = -INFINITY, m1 = -INFINITY;
        const float4* sp = (const float4*)(s_state + pbase);
        FWD_CHUNK(0, ta01_0, ta23_0, tb01_0, tb23_0)
        FWD_CHUNK(1, ta01_1, ta23_1, tb01_1, tb23_1)
        FWD_CHUNK(2, ta01_2, ta23_2, tb01_2, tb23_2)
        FWD_CHUNK(3, ta01_3, ta23_3, tb01_3, tb23_3)
        FWD_CHUNK(4, ta01_4, ta23_4, tb01_4, tb23_4)
        FWD_CHUNK(5, ta01_5, ta23_5, tb01_5, tb23_5)
        FWD_CHUNK(6, ta01_6, ta23_6, tb01_6, tb23_6)
        FWD_CHUNK(7, ta01_7, ta23_7, tb01_7, tb23_7)

        s_partial[g][c]  = m0;
        s_partial[g][c2] = m1;
        __syncthreads();
        if (tid < CRF_K) {
            float p0 = s_partial[0][tid], p1 = s_partial[1][tid];
            float p2 = s_partial[2][tid], p3 = s_partial[3][tid];
            float p4 = s_partial[4][tid], p5 = s_partial[5][tid];
            float p6 = s_partial[6][tid], p7 = s_partial[7][tid];
            float q0 = fmaxf(fmaxf(p0, p1), p2);    // max3
            float q1 = fmaxf(fmaxf(p3, p4), p5);    // max3
            float bv = fmaxf(fmaxf(fmaxf(q0, q1), p6), p7);
            s_state[tid] = bv + e_cur;
            M[((size_t)t * CRF_B + b) * CRF_K + tid] = bv;   // PRE-emission
            sp0 = p0; sp1 = p1; sp2 = p2; sp3 = p3;
            sp4 = p4; sp5 = p5; sp6 = p6; sp7 = p7; sbv = bv;
        }
        __syncthreads();
        e_cur = e_next;
    }

    // flush gid for the final row (t = CRF_T-1)
    if (gidp && tid < CRF_K) {
        int bg = 7;
        if (sp6 == sbv) bg = 6;
        if (sp5 == sbv) bg = 5;
        if (sp4 == sbv) bg = 4;
        if (sp3 == sbv) bg = 3;
        if (sp2 == sbv) bg = 2;
        if (sp1 == sbv) bg = 1;
        if (sp0 == sbv) bg = 0;
        int g1 = __shfl_down(bg, 1, 64);
        if ((tid & 1) == 0)
            gidp[((size_t)(CRF_T - 1) * CRF_B + b) * 128 + (tid >> 1)] =
                (unsigned char)(bg | (g1 << 4));
    }
}

// ---------------------------------------------------------------------------
// bp via gid: 512 blocks (b x cg4 x ts2) x 256 thr (4 waves, t1 stride 4).
// 64KB transposed trans tile; gid byte for next iteration prefetched.
// ---------------------------------------------------------------------------

#define BPG_CHUNK(j) { \
    float4 mm = M4[j]; float4 ee = E4[j]; \
    float s0 = mm.x + ee.x, s1 = mm.y + ee.y; \
    float s2 = mm.z + ee.z, s3 = mm.w + ee.w; \
    float t0v = s_tile[base + 4*(j) + 0][lane]; \
    float t1v = s_tile[base + 4*(j) + 1][lane]; \
    float t2v = s_tile[base + 4*(j) + 2][lane]; \
    float t3v = s_tile[base + 4*(j) + 3][lane]; \
    float v0 = s0 + t0v; if (v0 > best) { best = v0; arg = base + 4*(j); } \
    float v1 = s1 + t1v; if (v1 > best) { best = v1; arg = base + 4*(j) + 1; } \
    float v2 = s2 + t2v; if (v2 > best) { best = v2; arg = base + 4*(j) + 2; } \
    float v3 = s3 + t3v; if (v3 > best) { best = v3; arg = base + 4*(j) + 3; } }

#define BPG_CHUNK0(j) { \
    float4 ee = E4[j]; \
    float t0v = s_tile[base + 4*(j) + 0][lane]; \
    float t1v = s_tile[base + 4*(j) + 1][lane]; \
    float t2v = s_tile[base + 4*(j) + 2][lane]; \
    float t3v = s_tile[base + 4*(j) + 3][lane]; \
    float v0 = ee.x + t0v; if (v0 > best) { best = v0; arg = base + 4*(j); } \
    float v1 = ee.y + t1v; if (v1 > best) { best = v1; arg = base + 4*(j) + 1; } \
    float v2 = ee.z + t2v; if (v2 > best) { best = v2; arg = base + 4*(j) + 2; } \
    float v3 = ee.w + t3v; if (v3 > best) { best = v3; arg = base + 4*(j) + 3; } }

__global__ __launch_bounds__(256) void crf_bp_gid(
    const float* __restrict__ M, const float* __restrict__ em,
    const float* __restrict__ trans, const unsigned char* __restrict__ gidp,
    unsigned char* __restrict__ bp)
{
    const int b    = blockIdx.x >> 3;
    const int cg   = (blockIdx.x >> 1) & 3;
    const int ts   = blockIdx.x & 1;
    const int tid  = threadIdx.x;
    const int lane = tid & 63;
    const int w    = tid >> 6;      // wave 0..3

    __shared__ float s_tile[CRF_K][64];   // 64 KB: s_tile[prev][col]

    const int k0 = cg * 64;
    for (int idx = tid; idx < CRF_K * 64; idx += 256) {
        const int p = idx >> 6, cc = idx & 63;
        s_tile[p][cc] = trans[(size_t)p * CRF_K + k0 + cc];
    }
    __syncthreads();

    const int t_lo = ts * 512;
    const int t_hi = ts ? (CRF_T - 1) : 512;
    const int half = (k0 >> 1) + (lane >> 1);
    const int odd  = lane & 1;

    int t1 = t_lo + w;
    if (t1 >= t_hi) return;
    unsigned char gb = gidp[((size_t)(t1 + 1) * CRF_B + b) * 128 + half];

    for (; t1 < t_hi; t1 += 4) {
        const int tn = t1 + 4;
        unsigned char gb_next = 0;
        if (tn < t_hi)                         // prefetch next gid byte
            gb_next = gidp[((size_t)(tn + 1) * CRF_B + b) * 128 + half];

        const int g    = odd ? ((gb >> 4) & 7) : (gb & 7);
        const int base = g << 5;
        const float4* E4 =
            (const float4*)(em + ((size_t)b * CRF_T + t1) * CRF_K + base);
        float best = -INFINITY; int arg = base;
        if (t1 == 0) {                         // state[0] = em[0]
            BPG_CHUNK0(0) BPG_CHUNK0(1) BPG_CHUNK0(2) BPG_CHUNK0(3)
            BPG_CHUNK0(4) BPG_CHUNK0(5) BPG_CHUNK0(6) BPG_CHUNK0(7)
        } else {
            const float4* M4 =
                (const float4*)(M + ((size_t)t1 * CRF_B + b) * CRF_K + base);
            BPG_CHUNK(0) BPG_CHUNK(1) BPG_CHUNK(2) BPG_CHUNK(3)
            BPG_CHUNK(4) BPG_CHUNK(5) BPG_CHUNK(6) BPG_CHUNK(7)
        }
        bp[((size_t)b * (CRF_T - 1) + t1) * CRF_K + k0 + lane] =
            (unsigned char)arg;
        gb = gb_next;
    }
}

// ---------------------------------------------------------------------------
// Fallback-B backpointers: full-scan bp_matrix (proven), state = M+em.
// ---------------------------------------------------------------------------

__global__ __launch_bounds__(1024, 2) void crf_bp_matrix(
    const float* __restrict__ M, const float* __restrict__ em,
    const float* __restrict__ trans, unsigned char* __restrict__ bp)
{
    const int b   = blockIdx.x >> 4;
    const int seg = blockIdx.x & 15;
    const int tid = threadIdx.x;
    const int g   = tid >> 8;      // 0..3
    const int k   = tid & 255;

    __shared__ __align__(16) float s_row[CRF_K];
    __shared__ float s_pv[4][CRF_K];
    __shared__ int   s_pi[4][CRF_K];

    const int pbase = g * 64;
    float4 tr[16];
#pragma unroll
    for (int i = 0; i < 16; ++i) {
        const int p = pbase + 4 * i;
        tr[i].x = trans[(p + 0) * CRF_K + k];
        tr[i].y = trans[(p + 1) * CRF_K + k];
        tr[i].z = trans[(p + 2) * CRF_K + k];
        tr[i].w = trans[(p + 3) * CRF_K + k];
    }

    const int t_lo = seg * SEGLEN;
    const int t_hi = min(t_lo + SEGLEN, CRF_T - 1);
    unsigned char* bpb = bp + (size_t)b * (CRF_T - 1) * CRF_K;

    for (int t1 = t_lo; t1 < t_hi; ++t1) {
        if (tid < CRF_K) {
            float ev = em[((size_t)b * CRF_T + t1) * CRF_K + tid];
            float sv = ev;
            if (t1 > 0) sv = M[((size_t)t1 * CRF_B + b) * CRF_K + tid] + ev;
            s_row[tid] = sv;
        }
        __syncthreads();

        float best = -INFINITY;
        int   arg  = pbase;
        const float4* spp = (const float4*)(s_row + pbase);
#pragma unroll
        for (int i = 0; i < 16; ++i) {
            float4 st = spp[i];
            const int p = pbase + 4 * i;
            float s0 = st.x + tr[i].x;
            float s1 = st.y + tr[i].y;
            float s2 = st.z + tr[i].z;
            float s3 = st.w + tr[i].w;
            if (s0 > best) { best = s0; arg = p; }
            if (s1 > best) { best = s1; arg = p + 1; }
            if (s2 > best) { best = s2; arg = p + 2; }
            if (s3 > best) { best = s3; arg = p + 3; }
        }
        s_pv[g][k] = best;
        s_pi[g][k] = arg;
        __syncthreads();
        if (tid < CRF_K) {
            float bv = s_pv[0][tid];
            int   ba = s_pi[0][tid];
#pragma unroll
            for (int j = 1; j < 4; ++j) {
                float v = s_pv[j][tid];
                if (v > bv) { bv = v; ba = s_pi[j][tid]; }
            }
            bpb[(size_t)t1 * CRF_K + tid] = (unsigned char)ba;
        }
        __syncthreads();
    }
}

// ---------------------------------------------------------------------------
// Segmented chase (proven): seg_maps -> compose -> emit.
// ---------------------------------------------------------------------------

__global__ __launch_bounds__(256) void crf_seg_maps(
    const unsigned char* __restrict__ bp, unsigned char* __restrict__ maps)
{
    const int b   = blockIdx.x >> 4;
    const int s   = blockIdx.x & 15;
    const int tid = threadIdx.x;
    const int rows = (s == NSEG - 1) ? SEGLEN - 1 : SEGLEN;
    const int r0   = s * SEGLEN;

    __shared__ unsigned char lbp[SEGLEN][CRF_K];   // 16 KB

    const unsigned char* bpb = bp + (size_t)b * (CRF_T - 1) * CRF_K;
    const int nw = rows * 64;
    for (int w = tid; w < nw; w += 256) {
        const int r = w >> 6, cc = w & 63;
        ((unsigned int*)lbp[r])[cc] =
            ((const unsigned int*)(bpb + (size_t)(r0 + r) * CRF_K))[cc];
    }
    __syncthreads();

    int tag = tid;
    for (int j = rows - 1; j >= 0; --j) tag = lbp[j][tag];
    maps[((size_t)b * NSEG + s) * CRF_K + tid] = (unsigned char)tag;
}

__global__ __launch_bounds__(256) void crf_compose(
    const float* __restrict__ M, const float* __restrict__ em,
    const unsigned char* __restrict__ maps,
    int* __restrict__ exits, float* __restrict__ out)
{
    const int b   = blockIdx.x;
    const int tid = threadIdx.x;

    __shared__ float s_wv[4];
    __shared__ int   s_wi[4];

    float v = M[((size_t)(CRF_T - 1) * CRF_B + b) * CRF_K + tid]
            + em[((size_t)b * CRF_T + (CRF_T - 1)) * CRF_K + tid];
    int   i = tid;
#pragma unroll
    for (int off = 32; off >= 1; off >>= 1) {
        float ov = __shfl_xor(v, off, 64);
        int   oi = __shfl_xor(i, off, 64);
        if (ov > v || (ov == v && oi < i)) { v = ov; i = oi; }
    }
    const int lane = tid & 63, wv = tid >> 6;
    if (lane == 0) { s_wv[wv] = v; s_wi[wv] = i; }
    __syncthreads();
    if (tid == 0) {
        float bv = s_wv[0]; int bi = s_wi[0];
#pragma unroll
        for (int w = 1; w < 4; ++w)
            if (s_wv[w] > bv) { bv = s_wv[w]; bi = s_wi[w]; }
        out[(size_t)b * CRF_T + (CRF_T - 1)] = (float)bi;
        int E = bi;
        exits[b * NSEG + NSEG - 1] = E;
        const unsigned char* mb = maps + (size_t)b * NSEG * CRF_K;
        for (int s = NSEG - 1; s >= 1; --s) {
            E = mb[(size_t)s * CRF_K + E];
            exits[b * NSEG + s - 1] = E;
        }
    }
}

__global__ __launch_bounds__(256) void crf_emit(
    const unsigned char* __restrict__ bp, const int* __restrict__ exits,
    float* __restrict__ out)
{
    const int b   = blockIdx.x >> 4;
    const int s   = blockIdx.x & 15;
    const int tid = threadIdx.x;
    const int rows = (s == NSEG - 1) ? SEGLEN - 1 : SEGLEN;
    const int r0   = s * SEGLEN;

    __shared__ unsigned char lbp[SEGLEN][CRF_K];

    const unsigned char* bpb = bp + (size_t)b * (CRF_T - 1) * CRF_K;
    const int nw = rows * 64;
    for (int w = tid; w < nw; w += 256) {
        const int r = w >> 6, cc = w & 63;
        ((unsigned int*)lbp[r])[cc] =
            ((const unsigned int*)(bpb + (size_t)(r0 + r) * CRF_K))[cc];
    }
    __syncthreads();

    int tag = tid;
    const bool win = (tid == exits[b * NSEG + s]);
    for (int j = rows - 1; j >= 0; --j) {
        tag = lbp[j][tag];
        if (win) out[(size_t)b * CRF_T + r0 + j] = (float)tag;
    }
}

__global__ void crf_zero_out(float* __restrict__ out, int n)
{
    int i = blockIdx.x * blockDim.x + threadIdx.x;
    if (i < n) out[i] = 0.0f;
}

// ---------------------------------------------------------------------------

extern "C" void kernel_launch(void* const* d_in, const int* in_sizes, int n_in,
                              void* d_out, int out_size, void* d_ws, size_t ws_size,
                              hipStream_t stream) {
    (void)in_sizes; (void)n_in;
    const float* em    = (const float*)d_in[0];   // [B,T,K]
    const float* trans = (const float*)d_in[1];   // [K,K]
    float* out = (float*)d_out;                   // [B,T]

    const size_t M_bytes     = (size_t)CRF_T * CRF_B * CRF_K * sizeof(float); // 64 MB
    const size_t gid_bytes   = (size_t)CRF_T * CRF_B * 128;                   // 8.4 MB
    const size_t bp_bytes    = (size_t)CRF_B * (CRF_T - 1) * CRF_K;           // 16.75 MB
    const size_t maps_bytes  = (size_t)CRF_B * NSEG * CRF_K;                  // 256 KB
    const size_t exits_bytes = (size_t)CRF_B * NSEG * sizeof(int);            // 4 KB

    char* w = (char*)d_ws;
    if (ws_size >= M_bytes + gid_bytes + bp_bytes + maps_bytes + exits_bytes) {
        float*         M     = (float*)w;            w += M_bytes;
        unsigned char* gidp  = (unsigned char*)w;    w += gid_bytes;
        unsigned char* bp    = (unsigned char*)w;    w += bp_bytes;
        unsigned char* maps  = (unsigned char*)w;    w += maps_bytes;
        int*           exits = (int*)w;

        crf_forward_states<<<CRF_B, 1024, 0, stream>>>(em, trans, M, gidp);
        crf_bp_gid<<<CRF_B * 8, 256, 0, stream>>>(M, em, trans, gidp, bp);
        crf_seg_maps<<<CRF_B * NSEG, 256, 0, stream>>>(bp, maps);
        crf_compose<<<CRF_B, 256, 0, stream>>>(M, em, maps, exits, out);
        crf_emit<<<CRF_B * NSEG, 256, 0, stream>>>(bp, exits, out);
    } else if (ws_size >= M_bytes + bp_bytes + maps_bytes + exits_bytes) {
        float*         M     = (float*)w;            w += M_bytes;
        unsigned char* bp    = (unsigned char*)w;    w += bp_bytes;
        unsigned char* maps  = (unsigned char*)w;    w += maps_bytes;
        int*           exits = (int*)w;

        crf_forward_states<<<CRF_B, 1024, 0, stream>>>(em, trans, M, nullptr);
        crf_bp_matrix<<<CRF_B * NSEG, 1024, 0, stream>>>(M, em, trans, bp);
        crf_seg_maps<<<CRF_B * NSEG, 256, 0, stream>>>(bp, maps);
        crf_compose<<<CRF_B, 256, 0, stream>>>(M, em, maps, exits, out);
        crf_emit<<<CRF_B * NSEG, 256, 0, stream>>>(bp, exits, out);
    } else {
        crf_zero_out<<<(out_size + 255) / 256, 256, 0, stream>>>(out, out_size);
    }
}